// Round 1
// baseline (4052.114 us; speedup 1.0000x reference)
//
#include <hip/hip_runtime.h>
#include <cstdint>

// Problem constants (match reference setup_inputs)
#define NNODE 40000
#define NEDGE 120000
#define NHE   16384
#define CCH   512
#define MPAD  40064   // 313 * 128, padded row count for GEMM A operands

typedef __attribute__((ext_vector_type(8))) short bf16x8;
typedef __attribute__((ext_vector_type(4))) float f32x4;
typedef __attribute__((ext_vector_type(8))) unsigned short ushort8;

// ---------------------------------------------------------------- helpers
__device__ __forceinline__ unsigned short f2bf(float f) {
  unsigned int u = __float_as_uint(f);
  u += 0x7FFFu + ((u >> 16) & 1u);   // round-to-nearest-even
  return (unsigned short)(u >> 16);
}

__device__ __forceinline__ void g2l16(const void* g, void* l) {
  // async global->LDS, 16B per lane. LDS dest must be wave-uniform base + lane*16.
  __builtin_amdgcn_global_load_lds(
      (const __attribute__((address_space(1))) unsigned int*)(uintptr_t)g,
      (__attribute__((address_space(3))) unsigned int*)(unsigned int)(uintptr_t)l,
      16, 0, 0);
}

// ---------------------------------------------------------------- conversions
__global__ void cvt_bf16_pad(const float* __restrict__ in, unsigned short* __restrict__ out,
                             long nValid, long nTotal) {
  long i = ((long)blockIdx.x * blockDim.x + threadIdx.x) * 8;
  if (i >= nTotal) return;
  ushort8 r;
  if (i < nValid) {
    float4 a = *(const float4*)(in + i);
    float4 b = *(const float4*)(in + i + 4);
    r[0] = f2bf(a.x); r[1] = f2bf(a.y); r[2] = f2bf(a.z); r[3] = f2bf(a.w);
    r[4] = f2bf(b.x); r[5] = f2bf(b.y); r[6] = f2bf(b.z); r[7] = f2bf(b.w);
  } else {
    for (int j = 0; j < 8; ++j) r[j] = 0;
  }
  *(ushort8*)(out + i) = r;
}

// W [512][512] f32 row-major (y = x @ W) -> Wt [col][k] bf16
__global__ void transpose_cvt(const float* __restrict__ W, unsigned short* __restrict__ Wt) {
  int gid = blockIdx.x * 256 + threadIdx.x;     // 0 .. 512*512-1
  if (gid >= CCH * CCH) return;
  int i = gid >> 9, j = gid & 511;              // W[i][j]
  Wt[j * CCH + i] = f2bf(W[gid]);
}

// ---------------------------------------------------------------- GEMM (bf16 MFMA)
// C[M,512] = A[Mpad,512]bf16 @ Wt^T (Wt is [col][k]) + bias (+ addbuf), f32 out.
template <bool ADD>
__global__ __launch_bounds__(256, 2) void gemm_bf16(
    const unsigned short* __restrict__ A, const unsigned short* __restrict__ Bt,
    const float* __restrict__ bias, const float* __restrict__ addbuf,
    float* __restrict__ out, int M) {
  __shared__ unsigned short As[128 * 32];
  __shared__ unsigned short Bs[128 * 32];
  const int tid = threadIdx.x;
  const int lane = tid & 63;
  const int w = tid >> 6;
  const int wr = w >> 1, wc = w & 1;            // 2x2 waves -> 64x64 per wave
  const int row0 = blockIdx.y * 128;
  const int col0 = blockIdx.x * 128;

  f32x4 acc[4][4];
#pragma unroll
  for (int m = 0; m < 4; ++m)
#pragma unroll
    for (int n = 0; n < 4; ++n) acc[m][n] = f32x4{0.f, 0.f, 0.f, 0.f};

  const int c0 = w * 128 + lane;                // chunk id base (2 issues of 64 lanes)
  for (int kt = 0; kt < 512; kt += 32) {
#pragma unroll
    for (int j = 0; j < 2; ++j) {
      int c = c0 + j * 64;                      // 16B chunk: row = c>>2, k8 = (c&3)*8
      int r = c >> 2, k8 = (c & 3) << 3;
      g2l16(A  + (size_t)(row0 + r) * CCH + kt + k8, &As[c * 8]);
      g2l16(Bt + (size_t)(col0 + r) * CCH + kt + k8, &Bs[c * 8]);
    }
    __syncthreads();                            // drains vmcnt -> LDS ready
    bf16x8 a[4], b[4];
    const int r16 = lane & 15, kh = (lane >> 4) << 3;
#pragma unroll
    for (int m = 0; m < 4; ++m) a[m] = *(const bf16x8*)&As[(wr * 64 + m * 16 + r16) * 32 + kh];
#pragma unroll
    for (int n = 0; n < 4; ++n) b[n] = *(const bf16x8*)&Bs[(wc * 64 + n * 16 + r16) * 32 + kh];
#pragma unroll
    for (int m = 0; m < 4; ++m)
#pragma unroll
      for (int n = 0; n < 4; ++n)
        acc[m][n] = __builtin_amdgcn_mfma_f32_16x16x32_bf16(a[m], b[n], acc[m][n], 0, 0, 0);
    __syncthreads();
  }
  // epilogue: D row = (lane>>4)*4 + r, col = lane&15 (verified layout)
  const int cgrp = (lane >> 4) * 4;
#pragma unroll
  for (int n = 0; n < 4; ++n) {
    int col = col0 + wc * 64 + n * 16 + (lane & 15);
    float bv = bias[col];
#pragma unroll
    for (int m = 0; m < 4; ++m) {
#pragma unroll
      for (int r2 = 0; r2 < 4; ++r2) {
        int row = row0 + wr * 64 + m * 16 + cgrp + r2;
        if (row < M) {
          size_t idx = (size_t)row * CCH + col;
          float v = acc[m][n][r2] + bv;
          if (ADD) v += addbuf[idx];
          out[idx] = v;
        }
      }
    }
  }
}

// ---------------------------------------------------------------- scatters
// dst[dstIdx[e]] += src[srcIdx[e]]  (rows of 512 f32); 128 threads/edge, 4 f32/thread
__global__ void scatter_add_rows(const float* __restrict__ src, const int* __restrict__ srcIdx,
                                 const int* __restrict__ dstIdx, float* __restrict__ dst, int E) {
  long gid = (long)blockIdx.x * blockDim.x + threadIdx.x;
  int e = (int)(gid >> 7);
  if (e >= E) return;
  int c4 = ((int)gid & 127) << 2;
  int sn = srcIdx[e], dn = dstIdx[e];
  float4 v = *(const float4*)&src[(size_t)sn * CCH + c4];
  float* d = &dst[(size_t)dn * CCH + c4];
  atomicAdd(d + 0, v.x); atomicAdd(d + 1, v.y);
  atomicAdd(d + 2, v.z); atomicAdd(d + 3, v.w);
}

// node_out[nidx[e]] += he[hidx[e]] * alpha_norm(e,h)
__global__ void scatter_val(const float* __restrict__ he, const float* __restrict__ alpha,
                            const float* __restrict__ inv, const int* __restrict__ nidx,
                            const int* __restrict__ hidx, float* __restrict__ node_out, int E) {
  long gid = (long)blockIdx.x * blockDim.x + threadIdx.x;
  int e = (int)(gid >> 7);
  if (e >= E) return;
  int c4 = ((int)gid & 127) << 2;
  int h = c4 >> 6;
  float an = alpha[(size_t)e * 8 + h] * inv[h];
  float4 v = *(const float4*)&he[(size_t)hidx[e] * CCH + c4];
  float* d = &node_out[(size_t)nidx[e] * CCH + c4];
  atomicAdd(d + 0, v.x * an); atomicAdd(d + 1, v.y * an);
  atomicAdd(d + 2, v.z * an); atomicAdd(d + 3, v.w * an);
}

// ---------------------------------------------------------------- alpha = exp(q.k * scale), + per-head sums
__global__ void alpha_kernel(const float* __restrict__ Q, const float* __restrict__ he,
                             const int* __restrict__ nidx, const int* __restrict__ hidx,
                             float* __restrict__ alpha, float* __restrict__ sums, int E) {
  __shared__ float lsum[8];
  if (threadIdx.x < 8) lsum[threadIdx.x] = 0.f;
  __syncthreads();
  const int lane = threadIdx.x & 63;
  const int widx = threadIdx.x >> 6;            // 4 waves = 4 edges per block-iter
  const int h = lane >> 3, sub = lane & 7;
  const int d0 = lane * 8;
  for (int e = blockIdx.x * 4 + widx; e < E; e += gridDim.x * 4) {
    const float* qr = Q + (size_t)nidx[e] * CCH;
    const float* kr = he + (size_t)hidx[e] * CCH;
    float4 qa = *(const float4*)(qr + d0), qb = *(const float4*)(qr + d0 + 4);
    float4 ka = *(const float4*)(kr + d0), kb = *(const float4*)(kr + d0 + 4);
    float p = qa.x * ka.x + qa.y * ka.y + qa.z * ka.z + qa.w * ka.w +
              qb.x * kb.x + qb.y * kb.y + qb.z * kb.z + qb.w * kb.w;
    p += __shfl_xor(p, 1); p += __shfl_xor(p, 2); p += __shfl_xor(p, 4);
    if (sub == 0) {
      float a = __expf(p * 0.125f);             // scale = 1/sqrt(64); no max-sub needed (bounded logits)
      alpha[(size_t)e * 8 + h] = a;
      atomicAdd(&lsum[h], a);
    }
  }
  __syncthreads();
  if (threadIdx.x < 8) atomicAdd(&sums[threadIdx.x], lsum[threadIdx.x]);
}

__global__ void invert8(const float* __restrict__ sums, float* __restrict__ inv) {
  if (threadIdx.x < 8) inv[threadIdx.x] = 1.0f / sums[threadIdx.x];
}

// ---------------------------------------------------------------- LayerNorm (in-place, 1 wave / row)
__global__ void ln_kernel(float* __restrict__ y, const float* __restrict__ g,
                          const float* __restrict__ b, int nRows) {
  int row = blockIdx.x * 4 + (threadIdx.x >> 6);
  if (row >= nRows) return;
  int lane = threadIdx.x & 63;
  float* yr = y + (size_t)row * CCH;
  int d0 = lane * 8;
  float4 v0 = *(const float4*)(yr + d0);
  float4 v1 = *(const float4*)(yr + d0 + 4);
  float vv[8] = {v0.x, v0.y, v0.z, v0.w, v1.x, v1.y, v1.z, v1.w};
  float s = 0.f;
#pragma unroll
  for (int j = 0; j < 8; ++j) s += vv[j];
#pragma unroll
  for (int off = 1; off < 64; off <<= 1) s += __shfl_xor(s, off);
  float mu = s * (1.0f / 512.0f);
  float sq = 0.f;
#pragma unroll
  for (int j = 0; j < 8; ++j) { float d = vv[j] - mu; sq += d * d; }
#pragma unroll
  for (int off = 1; off < 64; off <<= 1) sq += __shfl_xor(sq, off);
  float rs = rsqrtf(sq * (1.0f / 512.0f) + 1e-5f);
  float4 g0 = *(const float4*)(g + d0), g1 = *(const float4*)(g + d0 + 4);
  float4 b0 = *(const float4*)(b + d0), b1 = *(const float4*)(b + d0 + 4);
  float gg[8] = {g0.x, g0.y, g0.z, g0.w, g1.x, g1.y, g1.z, g1.w};
  float bb[8] = {b0.x, b0.y, b0.z, b0.w, b1.x, b1.y, b1.z, b1.w};
  float o[8];
#pragma unroll
  for (int j = 0; j < 8; ++j) o[j] = gg[j] * (vv[j] - mu) * rs + bb[j];
  *(float4*)(yr + d0) = float4{o[0], o[1], o[2], o[3]};
  *(float4*)(yr + d0 + 4) = float4{o[4], o[5], o[6], o[7]};
}

// ---------------------------------------------------------------- host
extern "C" void kernel_launch(void* const* d_in, const int* in_sizes, int n_in,
                              void* d_out, int out_size, void* d_ws, size_t ws_size,
                              hipStream_t stream) {
  const float* x_a = (const float*)d_in[0];
  const float* x_b = (const float*)d_in[1];
  const int* nidx_a = (const int*)d_in[2];
  const int* hidx_a = (const int*)d_in[3];
  const int* nidx_b = (const int*)d_in[4];
  const int* hidx_b = (const int*)d_in[5];
  // per-type params: base 7 (a), 17 (b): kW,kb,qW,qb,aW,ab,sW,sb,lng,lnb
  const float *kW[2], *kb[2], *qW[2], *qb[2], *aW[2], *ab[2], *sW[2], *sb[2], *lng[2], *lnb[2];
  const float *xin[2] = {x_a, x_b};
  const int *nidx[2] = {nidx_a, nidx_b}, *hidx[2] = {hidx_a, hidx_b};
  for (int t = 0; t < 2; ++t) {
    int base = 7 + t * 10;
    kW[t] = (const float*)d_in[base + 0]; kb[t] = (const float*)d_in[base + 1];
    qW[t] = (const float*)d_in[base + 2]; qb[t] = (const float*)d_in[base + 3];
    aW[t] = (const float*)d_in[base + 4]; ab[t] = (const float*)d_in[base + 5];
    sW[t] = (const float*)d_in[base + 6]; sb[t] = (const float*)d_in[base + 7];
    lng[t] = (const float*)d_in[base + 8]; lnb[t] = (const float*)d_in[base + 9];
  }

  // workspace layout
  const size_t SZ_XBF = (size_t)MPAD * CCH * 2;       // 41,025,536
  const size_t SZ_WT = (size_t)CCH * CCH * 2;         // 524,288
  const size_t SZ_HE = (size_t)NHE * CCH * 4;         // 33,554,432
  const size_t SZ_BUFP = (size_t)MPAD * CCH * 4;      // 82,051,072
  const size_t SZ_NBF = SZ_XBF;
  const size_t SZ_ALPHA = (size_t)NEDGE * 8 * 4;      // 3,840,000
  size_t off = 0;
  auto take = [&](size_t sz) { size_t o = off; off = (off + sz + 255) & ~(size_t)255; return o; };
  size_t o_xbf[2]; o_xbf[0] = take(SZ_XBF); o_xbf[1] = take(SZ_XBF);
  size_t o_wt = take(8 * SZ_WT);
  size_t o_he = take(SZ_HE);
  size_t o_bufP = take(SZ_BUFP);
  size_t o_nbf = take(SZ_NBF);
  size_t o_alpha = take(SZ_ALPHA);
  size_t o_stats = take(256);
  if (ws_size < off) return;  // workspace too small -> fail loudly via zero output

  char* ws = (char*)d_ws;
  unsigned short* xbf[2] = {(unsigned short*)(ws + o_xbf[0]), (unsigned short*)(ws + o_xbf[1])};
  auto wt = [&](int slot) { return (unsigned short*)(ws + o_wt + (size_t)slot * SZ_WT); };
  float* he = (float*)(ws + o_he);
  float* bufP = (float*)(ws + o_bufP);
  unsigned short* nbf = (unsigned short*)(ws + o_nbf);
  float* alpha = (float*)(ws + o_alpha);
  float* sums = (float*)(ws + o_stats);
  float* inv = sums + 8;
  float* out = (float*)d_out;

  const long nValid = (long)NNODE * CCH, nTotal = (long)MPAD * CCH;
  const int cvtBlocks = (int)((nTotal / 8 + 255) / 256);
  const dim3 gemmGrid(4, MPAD / 128);
  const int scatBlocks = NEDGE * 128 / 256;

  // hyperedge accumulator
  hipMemsetAsync(he, 0, SZ_HE, stream);

  // convert inputs / weights to bf16
  cvt_bf16_pad<<<cvtBlocks, 256, 0, stream>>>(x_a, xbf[0], nValid, nTotal);
  cvt_bf16_pad<<<cvtBlocks, 256, 0, stream>>>(x_b, xbf[1], nValid, nTotal);
  for (int t = 0; t < 2; ++t) {
    transpose_cvt<<<1024, 256, 0, stream>>>(kW[t], wt(t * 4 + 0));
    transpose_cvt<<<1024, 256, 0, stream>>>(qW[t], wt(t * 4 + 1));
    transpose_cvt<<<1024, 256, 0, stream>>>(sW[t], wt(t * 4 + 2));
    transpose_cvt<<<1024, 256, 0, stream>>>(aW[t], wt(t * 4 + 3));
  }

  // he = sum over types of scatter(K)
  for (int t = 0; t < 2; ++t) {
    gemm_bf16<false><<<gemmGrid, 256, 0, stream>>>(xbf[t], wt(t * 4 + 0), kb[t], nullptr, bufP, NNODE);
    scatter_add_rows<<<scatBlocks, 256, 0, stream>>>(bufP, nidx[t], hidx[t], he, NEDGE);
  }

  // per-type attention + output
  for (int t = 0; t < 2; ++t) {
    float* dout_t = out + (size_t)t * NNODE * CCH;
    gemm_bf16<false><<<gemmGrid, 256, 0, stream>>>(xbf[t], wt(t * 4 + 1), qb[t], nullptr, bufP, NNODE);
    hipMemsetAsync(sums, 0, 64, stream);
    alpha_kernel<<<1024, 256, 0, stream>>>(bufP, he, nidx[t], hidx[t], alpha, sums, NEDGE);
    invert8<<<1, 64, 0, stream>>>(sums, inv);
    hipMemsetAsync(bufP, 0, SZ_BUFP, stream);   // node_out accumulator (reuses bufP)
    scatter_val<<<scatBlocks, 256, 0, stream>>>(he, alpha, inv, nidx[t], hidx[t], bufP, NEDGE);
    cvt_bf16_pad<<<cvtBlocks, 256, 0, stream>>>(bufP, nbf, nTotal, nTotal);  // node_out -> bf16
    // skip: S = x @ sW + sb  -> d_out (as temp)
    gemm_bf16<false><<<gemmGrid, 256, 0, stream>>>(xbf[t], wt(t * 4 + 2), sb[t], nullptr, dout_t, NNODE);
    // merged: node_out @ aW + ab + S, in place
    gemm_bf16<true><<<gemmGrid, 256, 0, stream>>>(nbf, wt(t * 4 + 3), ab[t], dout_t, dout_t, NNODE);
    ln_kernel<<<(NNODE + 3) / 4, 256, 0, stream>>>(dout_t, lng[t], lnb[t], NNODE);
  }
}

// Round 2
// 1252.128 us; speedup vs baseline: 3.2362x; 3.2362x over previous
//
#include <hip/hip_runtime.h>
#include <cstdint>

// Problem constants (match reference setup_inputs)
#define NNODE 40000
#define NEDGE 120000
#define NHE   16384
#define CCH   512
#define MPAD  40064   // 313 * 128, padded row count for GEMM A operands

typedef __attribute__((ext_vector_type(8))) short bf16x8;
typedef __attribute__((ext_vector_type(4))) float f32x4;
typedef __attribute__((ext_vector_type(8))) unsigned short ushort8;
typedef __attribute__((ext_vector_type(4))) unsigned short ushort4v;

// ---------------------------------------------------------------- helpers
__device__ __forceinline__ unsigned short f2bf(float f) {
  unsigned int u = __float_as_uint(f);
  u += 0x7FFFu + ((u >> 16) & 1u);   // round-to-nearest-even
  return (unsigned short)(u >> 16);
}

__device__ __forceinline__ void g2l16(const void* g, void* l) {
  // async global->LDS, 16B per lane. LDS dest must be wave-uniform base + lane*16.
  __builtin_amdgcn_global_load_lds(
      (const __attribute__((address_space(1))) unsigned int*)(uintptr_t)g,
      (__attribute__((address_space(3))) unsigned int*)(unsigned int)(uintptr_t)l,
      16, 0, 0);
}

// ---------------------------------------------------------------- conversions
__global__ void cvt_bf16_pad(const float* __restrict__ in, unsigned short* __restrict__ out,
                             long nValid, long nTotal) {
  long i = ((long)blockIdx.x * blockDim.x + threadIdx.x) * 8;
  if (i >= nTotal) return;
  ushort8 r;
  if (i < nValid) {
    float4 a = *(const float4*)(in + i);
    float4 b = *(const float4*)(in + i + 4);
    r[0] = f2bf(a.x); r[1] = f2bf(a.y); r[2] = f2bf(a.z); r[3] = f2bf(a.w);
    r[4] = f2bf(b.x); r[5] = f2bf(b.y); r[6] = f2bf(b.z); r[7] = f2bf(b.w);
  } else {
    for (int j = 0; j < 8; ++j) r[j] = 0;
  }
  *(ushort8*)(out + i) = r;
}

// W [512][512] f32 row-major (y = x @ W) -> Wt [col][ldDst], k offset kOff, bf16
__global__ void transpose_cvt(const float* __restrict__ W, unsigned short* __restrict__ Wt,
                              int ldDst, int kOff) {
  int gid = blockIdx.x * 256 + threadIdx.x;     // 0 .. 512*512-1
  if (gid >= CCH * CCH) return;
  int i = gid >> 9, j = gid & 511;              // W[i][j]
  Wt[(size_t)j * ldDst + kOff + i] = f2bf(W[gid]);
}

// ---------------------------------------------------------------- CSR build
__global__ void hist_kernel(const int* __restrict__ idx, int* __restrict__ cnt, int E) {
  int e = blockIdx.x * 256 + threadIdx.x;
  if (e < E) atomicAdd(&cnt[idx[e]], 1);
}

// single-block exclusive scan, base[n] = total
__global__ void scan_kernel(const int* __restrict__ cnt, int* __restrict__ base, int n) {
  __shared__ int part[1024];
  int tid = threadIdx.x;
  int chunk = (n + 1023) >> 10;
  int lo = tid * chunk;
  int hi = lo + chunk; if (hi > n) hi = n;
  int s = 0;
  for (int i = lo; i < hi; ++i) s += cnt[i];
  part[tid] = s;
  __syncthreads();
  for (int off = 1; off < 1024; off <<= 1) {
    int v = (tid >= off) ? part[tid - off] : 0;
    __syncthreads();
    part[tid] += v;
    __syncthreads();
  }
  int excl = (tid == 0) ? 0 : part[tid - 1];
  for (int i = lo; i < hi; ++i) { base[i] = excl; excl += cnt[i]; }
  if (tid == 0) base[n] = part[1023];
}

__global__ void fill_perm(const int* __restrict__ idx, const int* __restrict__ base,
                          int* __restrict__ cursor, int* __restrict__ perm, int E) {
  int e = blockIdx.x * 256 + threadIdx.x;
  if (e >= E) return;
  int b = idx[e];
  int p = atomicAdd(&cursor[b], 1);
  perm[base[b] + p] = e;
}

// ---------------------------------------------------------------- gathers
// he[h] (+)= sum over CSR bucket of K[node_idx[e]]; 128 threads per row
template <bool ADD>
__global__ void he_gather(const float* __restrict__ K, const int* __restrict__ nidx,
                          const int* __restrict__ base, const int* __restrict__ perm,
                          float* __restrict__ he) {
  int h = blockIdx.x * 2 + (threadIdx.x >> 7);
  if (h >= NHE) return;
  int t = threadIdx.x & 127;
  int c4 = t << 2;
  float4 acc;
  if (ADD) acc = *(const float4*)&he[(size_t)h * CCH + c4];
  else acc = float4{0.f, 0.f, 0.f, 0.f};
  int b1 = base[h + 1];
  for (int i = base[h]; i < b1; ++i) {
    int e = perm[i];
    int n = nidx[e];
    float4 v = *(const float4*)&K[(size_t)n * CCH + c4];
    acc.x += v.x; acc.y += v.y; acc.z += v.z; acc.w += v.w;
  }
  *(float4*)&he[(size_t)h * CCH + c4] = acc;
}

// alpha[e,h] = exp(scale * q[node] . he[hidx[e]]) using node-CSR (Q row reused)
__global__ void alpha_kernel(const float* __restrict__ Q, const float* __restrict__ he,
                             const int* __restrict__ hidx, const int* __restrict__ base,
                             const int* __restrict__ perm, float* __restrict__ alpha,
                             float* __restrict__ sums, int nNodes) {
  __shared__ float lsum[8];
  if (threadIdx.x < 8) lsum[threadIdx.x] = 0.f;
  __syncthreads();
  int node = blockIdx.x * 4 + (threadIdx.x >> 6);
  int lane = threadIdx.x & 63;
  int h = lane >> 3, sub = lane & 7;
  int d0 = lane * 8;
  float part = 0.f;
  if (node < nNodes) {
    const float* qr = Q + (size_t)node * CCH;
    float4 qa = *(const float4*)(qr + d0), qb = *(const float4*)(qr + d0 + 4);
    int b1 = base[node + 1];
    for (int i = base[node]; i < b1; ++i) {
      int e = perm[i];
      const float* kr = he + (size_t)hidx[e] * CCH;
      float4 ka = *(const float4*)(kr + d0), kb = *(const float4*)(kr + d0 + 4);
      float p = qa.x * ka.x + qa.y * ka.y + qa.z * ka.z + qa.w * ka.w +
                qb.x * kb.x + qb.y * kb.y + qb.z * kb.z + qb.w * kb.w;
      p += __shfl_xor(p, 1); p += __shfl_xor(p, 2); p += __shfl_xor(p, 4);
      if (sub == 0) {
        float a = __expf(p * 0.125f);   // scale = 1/sqrt(64); logits bounded, no max pass
        alpha[(size_t)e * 8 + h] = a;
        part += a;
      }
    }
  }
  if (sub == 0) atomicAdd(&lsum[h], part);
  __syncthreads();
  if (threadIdx.x < 8) atomicAdd(&sums[threadIdx.x], lsum[threadIdx.x]);
}

__global__ void invert8(const float* __restrict__ sums, float* __restrict__ inv) {
  if (threadIdx.x < 8) inv[threadIdx.x] = 1.0f / sums[threadIdx.x];
}

// node_out[n] = sum alpha_norm(e,h) * he[hidx[e]]; writes bf16 padded rows [MPAD]
__global__ void node_gather(const float* __restrict__ he, const float* __restrict__ alpha,
                            const float* __restrict__ inv, const int* __restrict__ hidx,
                            const int* __restrict__ base, const int* __restrict__ perm,
                            unsigned short* __restrict__ nbf) {
  int n = blockIdx.x * 2 + (threadIdx.x >> 7);
  if (n >= MPAD) return;
  int t = threadIdx.x & 127;
  int c4 = t << 2, h = c4 >> 6;
  float ax = 0.f, ay = 0.f, az = 0.f, aw = 0.f;
  if (n < NNODE) {
    float iv = inv[h];
    int b1 = base[n + 1];
    for (int i = base[n]; i < b1; ++i) {
      int e = perm[i];
      float an = alpha[(size_t)e * 8 + h] * iv;
      float4 v = *(const float4*)&he[(size_t)hidx[e] * CCH + c4];
      ax += v.x * an; ay += v.y * an; az += v.z * an; aw += v.w * an;
    }
  }
  ushort4v r = {f2bf(ax), f2bf(ay), f2bf(az), f2bf(aw)};
  *(ushort4v*)&nbf[(size_t)n * CCH + c4] = r;
}

// ---------------------------------------------------------------- GEMM (bf16 MFMA)
// out[M,512] = [A0 | A1][Mpad,KDIM] @ Bt^T + bias (+bias2), f32 out.
// A0 covers k in [0,512), A1 covers k in [512,KDIM). Both are [*, 512] bf16.
template <int KDIM>
__global__ __launch_bounds__(256, 2) void gemm_bf16(
    const unsigned short* __restrict__ A0, const unsigned short* __restrict__ A1,
    const unsigned short* __restrict__ Bt, const float* __restrict__ bias,
    const float* __restrict__ bias2, float* __restrict__ out, int M) {
  __shared__ unsigned short As[128 * 32];
  __shared__ unsigned short Bs[128 * 32];
  const int tid = threadIdx.x;
  const int lane = tid & 63;
  const int w = tid >> 6;
  const int wr = w >> 1, wc = w & 1;            // 2x2 waves -> 64x64 per wave
  const int row0 = blockIdx.y * 128;
  const int col0 = blockIdx.x * 128;

  f32x4 acc[4][4];
#pragma unroll
  for (int m = 0; m < 4; ++m)
#pragma unroll
    for (int n = 0; n < 4; ++n) acc[m][n] = f32x4{0.f, 0.f, 0.f, 0.f};

  const int c0 = w * 128 + lane;
  for (int kt = 0; kt < KDIM; kt += 32) {
#pragma unroll
    for (int j = 0; j < 2; ++j) {
      int c = c0 + j * 64;                      // 16B chunk: row = c>>2, k8 = (c&3)*8
      int r = c >> 2, k8 = (c & 3) << 3;
      const unsigned short* asrc;
      if (KDIM == 512 || kt < 512)
        asrc = A0 + (size_t)(row0 + r) * 512 + kt + k8;
      else
        asrc = A1 + (size_t)(row0 + r) * 512 + (kt - 512) + k8;
      g2l16(asrc, &As[c * 8]);
      g2l16(Bt + (size_t)(col0 + r) * KDIM + kt + k8, &Bs[c * 8]);
    }
    __syncthreads();
    bf16x8 a[4], b[4];
    const int r16 = lane & 15, kh = (lane >> 4) << 3;
#pragma unroll
    for (int m = 0; m < 4; ++m) a[m] = *(const bf16x8*)&As[(wr * 64 + m * 16 + r16) * 32 + kh];
#pragma unroll
    for (int n = 0; n < 4; ++n) b[n] = *(const bf16x8*)&Bs[(wc * 64 + n * 16 + r16) * 32 + kh];
#pragma unroll
    for (int m = 0; m < 4; ++m)
#pragma unroll
      for (int n = 0; n < 4; ++n)
        acc[m][n] = __builtin_amdgcn_mfma_f32_16x16x32_bf16(a[m], b[n], acc[m][n], 0, 0, 0);
    __syncthreads();
  }
  const int cgrp = (lane >> 4) * 4;
#pragma unroll
  for (int n = 0; n < 4; ++n) {
    int col = col0 + wc * 64 + n * 16 + (lane & 15);
    float bv = bias[col];
    if (bias2) bv += bias2[col];
#pragma unroll
    for (int m = 0; m < 4; ++m) {
#pragma unroll
      for (int r2 = 0; r2 < 4; ++r2) {
        int row = row0 + wr * 64 + m * 16 + cgrp + r2;
        if (row < M) out[(size_t)row * CCH + col] = acc[m][n][r2] + bv;
      }
    }
  }
}

// ---------------------------------------------------------------- LayerNorm (in-place, 1 wave / row)
__global__ void ln_kernel(float* __restrict__ y, const float* __restrict__ g,
                          const float* __restrict__ b, int nRows) {
  int row = blockIdx.x * 4 + (threadIdx.x >> 6);
  if (row >= nRows) return;
  int lane = threadIdx.x & 63;
  float* yr = y + (size_t)row * CCH;
  int d0 = lane * 8;
  float4 v0 = *(const float4*)(yr + d0);
  float4 v1 = *(const float4*)(yr + d0 + 4);
  float vv[8] = {v0.x, v0.y, v0.z, v0.w, v1.x, v1.y, v1.z, v1.w};
  float s = 0.f;
#pragma unroll
  for (int j = 0; j < 8; ++j) s += vv[j];
#pragma unroll
  for (int off = 1; off < 64; off <<= 1) s += __shfl_xor(s, off);
  float mu = s * (1.0f / 512.0f);
  float sq = 0.f;
#pragma unroll
  for (int j = 0; j < 8; ++j) { float d = vv[j] - mu; sq += d * d; }
#pragma unroll
  for (int off = 1; off < 64; off <<= 1) sq += __shfl_xor(sq, off);
  float rs = rsqrtf(sq * (1.0f / 512.0f) + 1e-5f);
  float4 g0 = *(const float4*)(g + d0), g1 = *(const float4*)(g + d0 + 4);
  float4 b0 = *(const float4*)(b + d0), b1 = *(const float4*)(b + d0 + 4);
  float gg[8] = {g0.x, g0.y, g0.z, g0.w, g1.x, g1.y, g1.z, g1.w};
  float bb[8] = {b0.x, b0.y, b0.z, b0.w, b1.x, b1.y, b1.z, b1.w};
  float o[8];
#pragma unroll
  for (int j = 0; j < 8; ++j) o[j] = gg[j] * (vv[j] - mu) * rs + bb[j];
  *(float4*)(yr + d0) = float4{o[0], o[1], o[2], o[3]};
  *(float4*)(yr + d0 + 4) = float4{o[4], o[5], o[6], o[7]};
}

// ---------------------------------------------------------------- host
extern "C" void kernel_launch(void* const* d_in, const int* in_sizes, int n_in,
                              void* d_out, int out_size, void* d_ws, size_t ws_size,
                              hipStream_t stream) {
  const float* x_a = (const float*)d_in[0];
  const float* x_b = (const float*)d_in[1];
  const int* nidx[2] = {(const int*)d_in[2], (const int*)d_in[4]};
  const int* hidx[2] = {(const int*)d_in[3], (const int*)d_in[5]};
  const float *kW[2], *kb[2], *qW[2], *qb[2], *aW[2], *ab[2], *sW[2], *sb[2], *lng[2], *lnb[2];
  for (int t = 0; t < 2; ++t) {
    int base = 7 + t * 10;
    kW[t] = (const float*)d_in[base + 0]; kb[t] = (const float*)d_in[base + 1];
    qW[t] = (const float*)d_in[base + 2]; qb[t] = (const float*)d_in[base + 3];
    aW[t] = (const float*)d_in[base + 4]; ab[t] = (const float*)d_in[base + 5];
    sW[t] = (const float*)d_in[base + 6]; sb[t] = (const float*)d_in[base + 7];
    lng[t] = (const float*)d_in[base + 8]; lnb[t] = (const float*)d_in[base + 9];
  }

  // ---------------- workspace layout
  const size_t SZ_XBF = (size_t)MPAD * CCH * 2;         // 41 MB
  const size_t SZ_WT_TYPE = (size_t)512 * 2048 * 2;     // 2 MB: k(512x512) q(512x512) comb(512x1024)
  const size_t SZ_HE = (size_t)NHE * CCH * 4;           // 33.5 MB
  const size_t SZ_BUFP = (size_t)MPAD * CCH * 4;        // 82 MB (Q/K f32; nbf aliases front half)
  const size_t SZ_ALPHA = (size_t)NEDGE * 8 * 4;        // 3.84 MB
  size_t off = 0;
  auto take = [&](size_t sz) { size_t o = off; off = (off + sz + 255) & ~(size_t)255; return o; };
  size_t o_xbf[2]; o_xbf[0] = take(SZ_XBF); o_xbf[1] = take(SZ_XBF);
  size_t o_wt = take(2 * SZ_WT_TYPE);
  size_t o_he = take(SZ_HE);
  size_t o_bufP = take(SZ_BUFP);
  size_t o_alpha = take(SZ_ALPHA);
  size_t o_stats = take(256);
  size_t o_cnt = take((size_t)NNODE * 4);
  size_t o_baseH[2]; o_baseH[0] = take((NHE + 1) * 4); o_baseH[1] = take((NHE + 1) * 4);
  size_t o_baseN[2]; o_baseN[0] = take((NNODE + 1) * 4); o_baseN[1] = take((NNODE + 1) * 4);
  size_t o_permH[2]; o_permH[0] = take((size_t)NEDGE * 4); o_permH[1] = take((size_t)NEDGE * 4);
  size_t o_permN[2]; o_permN[0] = take((size_t)NEDGE * 4); o_permN[1] = take((size_t)NEDGE * 4);
  if (ws_size < off) return;

  char* ws = (char*)d_ws;
  unsigned short* xbf[2] = {(unsigned short*)(ws + o_xbf[0]), (unsigned short*)(ws + o_xbf[1])};
  auto wtK = [&](int t) { return (unsigned short*)(ws + o_wt + (size_t)t * SZ_WT_TYPE); };
  auto wtQ = [&](int t) { return wtK(t) + 512 * 512; };
  auto wtC = [&](int t) { return wtK(t) + 2 * 512 * 512; };  // combined [col][1024]: aW at 0, sW at 512
  float* he = (float*)(ws + o_he);
  float* bufP = (float*)(ws + o_bufP);
  unsigned short* nbf = (unsigned short*)(ws + o_bufP);  // aliases bufP (used after bufP is dead)
  float* alpha = (float*)(ws + o_alpha);
  float* sums = (float*)(ws + o_stats);
  float* inv = sums + 8;
  int* cnt = (int*)(ws + o_cnt);
  int* baseH[2] = {(int*)(ws + o_baseH[0]), (int*)(ws + o_baseH[1])};
  int* baseN[2] = {(int*)(ws + o_baseN[0]), (int*)(ws + o_baseN[1])};
  int* permH[2] = {(int*)(ws + o_permH[0]), (int*)(ws + o_permH[1])};
  int* permN[2] = {(int*)(ws + o_permN[0]), (int*)(ws + o_permN[1])};
  float* out = (float*)d_out;

  const long nValid = (long)NNODE * CCH, nTotal = (long)MPAD * CCH;
  const int cvtBlocks = (int)((nTotal / 8 + 255) / 256);
  const dim3 gemmGrid(4, MPAD / 128);
  const int histBlocks = (NEDGE + 255) / 256;

  // ---------------- CSR builds (indices only)
  for (int t = 0; t < 2; ++t) {
    hipMemsetAsync(cnt, 0, (size_t)NNODE * 4, stream);
    hist_kernel<<<histBlocks, 256, 0, stream>>>(hidx[t], cnt, NEDGE);
    scan_kernel<<<1, 1024, 0, stream>>>(cnt, baseH[t], NHE);
    hipMemsetAsync(cnt, 0, (size_t)NNODE * 4, stream);
    fill_perm<<<histBlocks, 256, 0, stream>>>(hidx[t], baseH[t], cnt, permH[t], NEDGE);
    hipMemsetAsync(cnt, 0, (size_t)NNODE * 4, stream);
    hist_kernel<<<histBlocks, 256, 0, stream>>>(nidx[t], cnt, NEDGE);
    scan_kernel<<<1, 1024, 0, stream>>>(cnt, baseN[t], NNODE);
    hipMemsetAsync(cnt, 0, (size_t)NNODE * 4, stream);
    fill_perm<<<histBlocks, 256, 0, stream>>>(nidx[t], baseN[t], cnt, permN[t], NEDGE);
  }

  // ---------------- convert inputs / weights to bf16
  cvt_bf16_pad<<<cvtBlocks, 256, 0, stream>>>(x_a, xbf[0], nValid, nTotal);
  cvt_bf16_pad<<<cvtBlocks, 256, 0, stream>>>(x_b, xbf[1], nValid, nTotal);
  for (int t = 0; t < 2; ++t) {
    transpose_cvt<<<1024, 256, 0, stream>>>(kW[t], wtK(t), 512, 0);
    transpose_cvt<<<1024, 256, 0, stream>>>(qW[t], wtQ(t), 512, 0);
    transpose_cvt<<<1024, 256, 0, stream>>>(aW[t], wtC(t), 1024, 0);
    transpose_cvt<<<1024, 256, 0, stream>>>(sW[t], wtC(t), 1024, 512);
  }

  // ---------------- he = gather(K_a) then += gather(K_b)
  gemm_bf16<512><<<gemmGrid, 256, 0, stream>>>(xbf[0], xbf[0], wtK(0), kb[0], nullptr, bufP, NNODE);
  he_gather<false><<<NHE / 2, 256, 0, stream>>>(bufP, nidx[0], baseH[0], permH[0], he);
  gemm_bf16<512><<<gemmGrid, 256, 0, stream>>>(xbf[1], xbf[1], wtK(1), kb[1], nullptr, bufP, NNODE);
  he_gather<true><<<NHE / 2, 256, 0, stream>>>(bufP, nidx[1], baseH[1], permH[1], he);

  // ---------------- per-type attention + output
  for (int t = 0; t < 2; ++t) {
    float* dout_t = out + (size_t)t * NNODE * CCH;
    gemm_bf16<512><<<gemmGrid, 256, 0, stream>>>(xbf[t], xbf[t], wtQ(t), qb[t], nullptr, bufP, NNODE);
    hipMemsetAsync(sums, 0, 64, stream);
    alpha_kernel<<<(NNODE + 3) / 4, 256, 0, stream>>>(bufP, he, hidx[t], baseN[t], permN[t],
                                                      alpha, sums, NNODE);
    invert8<<<1, 64, 0, stream>>>(sums, inv);
    // node_out (bf16, padded) — writes into nbf which aliases bufP (Q no longer needed)
    node_gather<<<MPAD / 2, 256, 0, stream>>>(he, alpha, inv, hidx[t], baseN[t], permN[t], nbf);
    // fused: out = node_out @ aW + ab + x @ sW + sb   (K = 1024)
    gemm_bf16<1024><<<gemmGrid, 256, 0, stream>>>(nbf, xbf[t], wtC(t), ab[t], sb[t], dout_t, NNODE);
    ln_kernel<<<(NNODE + 3) / 4, 256, 0, stream>>>(dout_t, lng[t], lnb[t], NNODE);
  }
}

// Round 3
// 1001.263 us; speedup vs baseline: 4.0470x; 1.2505x over previous
//
#include <hip/hip_runtime.h>
#include <cstdint>

// Problem constants (match reference setup_inputs)
#define NNODE 40000
#define NEDGE 120000
#define NHE   16384
#define CCH   512
#define MPAD  40064   // 313 * 128, padded row count for GEMM A operands

typedef __attribute__((ext_vector_type(8))) short bf16x8;
typedef __attribute__((ext_vector_type(4))) float f32x4;
typedef __attribute__((ext_vector_type(8))) unsigned short ushort8;
typedef __attribute__((ext_vector_type(4))) unsigned short ushort4v;

// ---------------------------------------------------------------- helpers
__device__ __forceinline__ unsigned short f2bf(float f) {
  unsigned int u = __float_as_uint(f);
  u += 0x7FFFu + ((u >> 16) & 1u);   // round-to-nearest-even
  return (unsigned short)(u >> 16);
}
__device__ __forceinline__ float bf2f(unsigned short u) {
  return __uint_as_float((unsigned int)u << 16);
}

__device__ __forceinline__ void g2l16(const void* g, void* l) {
  // async global->LDS, 16B per lane. LDS dest must be wave-uniform base + lane*16.
  __builtin_amdgcn_global_load_lds(
      (const __attribute__((address_space(1))) unsigned int*)(uintptr_t)g,
      (__attribute__((address_space(3))) unsigned int*)(unsigned int)(uintptr_t)l,
      16, 0, 0);
}

// ---------------------------------------------------------------- conversions
__global__ void cvt_bf16_pad(const float* __restrict__ in, unsigned short* __restrict__ out,
                             long nValid, long nTotal) {
  long i = ((long)blockIdx.x * blockDim.x + threadIdx.x) * 8;
  if (i >= nTotal) return;
  ushort8 r;
  if (i < nValid) {
    float4 a = *(const float4*)(in + i);
    float4 b = *(const float4*)(in + i + 4);
    r[0] = f2bf(a.x); r[1] = f2bf(a.y); r[2] = f2bf(a.z); r[3] = f2bf(a.w);
    r[4] = f2bf(b.x); r[5] = f2bf(b.y); r[6] = f2bf(b.z); r[7] = f2bf(b.w);
  } else {
    for (int j = 0; j < 8; ++j) r[j] = 0;
  }
  *(ushort8*)(out + i) = r;
}

// W [512][512] f32 row-major (y = x @ W) -> Wt [col][ldDst], k offset kOff, bf16
__global__ void transpose_cvt(const float* __restrict__ W, unsigned short* __restrict__ Wt,
                              int ldDst, int kOff) {
  int gid = blockIdx.x * 256 + threadIdx.x;     // 0 .. 512*512-1
  if (gid >= CCH * CCH) return;
  int i = gid >> 9, j = gid & 511;              // W[i][j]
  Wt[(size_t)j * ldDst + kOff + i] = f2bf(W[gid]);
}

// ---------------------------------------------------------------- CSR build
__global__ void hist_kernel(const int* __restrict__ idx, int* __restrict__ cnt, int E) {
  int e = blockIdx.x * 256 + threadIdx.x;
  if (e < E) atomicAdd(&cnt[idx[e]], 1);
}

// single-block exclusive scan, base[n] = total
__global__ void scan_kernel(const int* __restrict__ cnt, int* __restrict__ base, int n) {
  __shared__ int part[1024];
  int tid = threadIdx.x;
  int chunk = (n + 1023) >> 10;
  int lo = tid * chunk;
  int hi = lo + chunk; if (hi > n) hi = n;
  int s = 0;
  for (int i = lo; i < hi; ++i) s += cnt[i];
  part[tid] = s;
  __syncthreads();
  for (int off = 1; off < 1024; off <<= 1) {
    int v = (tid >= off) ? part[tid - off] : 0;
    __syncthreads();
    part[tid] += v;
    __syncthreads();
  }
  int excl = (tid == 0) ? 0 : part[tid - 1];
  for (int i = lo; i < hi; ++i) { base[i] = excl; excl += cnt[i]; }
  if (tid == 0) base[n] = part[1023];
}

// bucket by bidx[e], store val[e] into the slot (no edge-id indirection later)
__global__ void fill_val(const int* __restrict__ bidx, const int* __restrict__ val,
                         const int* __restrict__ base, int* __restrict__ cursor,
                         int* __restrict__ out, int E) {
  int e = blockIdx.x * 256 + threadIdx.x;
  if (e >= E) return;
  int b = bidx[e];
  int p = atomicAdd(&cursor[b], 1);
  out[base[b] + p] = val[e];
}

// ---------------------------------------------------------------- Xagg gather
// Xagg[h] (+)= sum over bucket of x_bf16[node]; written as bf16. 128 thr/row.
template <bool ADD>
__global__ void xagg_gather(const unsigned short* __restrict__ X, const int* __restrict__ nArr,
                            const int* __restrict__ base, unsigned short* __restrict__ Xagg) {
  int h = blockIdx.x * 2 + (threadIdx.x >> 7);
  if (h >= NHE) return;
  int sub = threadIdx.x & 127;
  int c4 = sub << 2;
  float ax = 0.f, ay = 0.f, az = 0.f, aw = 0.f;
  if (ADD) {
    ushort4v p = *(const ushort4v*)&Xagg[(size_t)h * CCH + c4];
    ax = bf2f(p[0]); ay = bf2f(p[1]); az = bf2f(p[2]); aw = bf2f(p[3]);
  }
  int b1 = base[h + 1];
  for (int i = base[h]; i < b1; ++i) {
    int n = nArr[i];
    ushort4v v = *(const ushort4v*)&X[(size_t)n * CCH + c4];
    ax += bf2f(v[0]); ay += bf2f(v[1]); az += bf2f(v[2]); aw += bf2f(v[3]);
  }
  ushort4v r = {f2bf(ax), f2bf(ay), f2bf(az), f2bf(aw)};
  *(ushort4v*)&Xagg[(size_t)h * CCH + c4] = r;
}

// ---------------------------------------------------------------- fused attention
// Per node: acc = sum_e exp(scale * q.he[h_e]) * he[h_e]  (UNNORMALIZED),
// per-head exp-sums -> per-block partials (no global atomics).
__global__ void fused_attn(const float* __restrict__ Q, const float* __restrict__ he,
                           const int* __restrict__ hArr, const int* __restrict__ base,
                           float* __restrict__ nout, float* __restrict__ partials) {
  __shared__ float lsum[8];
  if (threadIdx.x < 8) lsum[threadIdx.x] = 0.f;
  __syncthreads();
  int node = blockIdx.x * 2 + (threadIdx.x >> 7);
  int sub = threadIdx.x & 127;
  int c4 = sub << 2, h = sub >> 4;
  float psum = 0.f;
  if (node < NNODE) {
    const float4 q = *(const float4*)&Q[(size_t)node * CCH + c4];
    float4 acc = {0.f, 0.f, 0.f, 0.f};
    int b1 = base[node + 1];
    for (int i = base[node]; i < b1; ++i) {
      int hid = hArr[i];
      float4 k = *(const float4*)&he[(size_t)hid * CCH + c4];
      float d = q.x * k.x + q.y * k.y + q.z * k.z + q.w * k.w;
      d += __shfl_xor(d, 1); d += __shfl_xor(d, 2);
      d += __shfl_xor(d, 4); d += __shfl_xor(d, 8);
      float a = __expf(d * 0.125f);   // scale = 1/sqrt(64); logits bounded, no max pass
      psum += a;
      acc.x += a * k.x; acc.y += a * k.y; acc.z += a * k.z; acc.w += a * k.w;
    }
    *(float4*)&nout[(size_t)node * CCH + c4] = acc;
  }
  if ((sub & 15) == 0) atomicAdd(&lsum[h], psum);
  __syncthreads();
  if (threadIdx.x < 8) partials[(size_t)blockIdx.x * 8 + threadIdx.x] = lsum[threadIdx.x];
}

// partials[nb][8] -> inv[8]; one block per head
__global__ void reduce_partials(const float* __restrict__ partials, float* __restrict__ inv, int nb) {
  __shared__ float ls[256];
  int h = blockIdx.x;
  float s = 0.f;
  for (int i = threadIdx.x; i < nb; i += 256) s += partials[(size_t)i * 8 + h];
  ls[threadIdx.x] = s;
  __syncthreads();
  for (int off = 128; off > 0; off >>= 1) {
    if (threadIdx.x < off) ls[threadIdx.x] += ls[threadIdx.x + off];
    __syncthreads();
  }
  if (threadIdx.x == 0) inv[h] = 1.0f / ls[0];
}

// nbf[n][c] = bf16( nout[n][c] * inv[head(c)] ), zero pad rows
__global__ void norm_cvt(const float* __restrict__ nout, const float* __restrict__ inv,
                         unsigned short* __restrict__ nbf) {
  long i = ((long)blockIdx.x * 256 + threadIdx.x) * 8;
  if (i >= (long)MPAD * CCH) return;
  ushort8 r;
  if (i < (long)NNODE * CCH) {
    int h = ((int)(i & 511)) >> 6;
    float iv = inv[h];
    float4 a = *(const float4*)(nout + i);
    float4 b = *(const float4*)(nout + i + 4);
    r[0] = f2bf(a.x * iv); r[1] = f2bf(a.y * iv); r[2] = f2bf(a.z * iv); r[3] = f2bf(a.w * iv);
    r[4] = f2bf(b.x * iv); r[5] = f2bf(b.y * iv); r[6] = f2bf(b.z * iv); r[7] = f2bf(b.w * iv);
  } else {
    for (int j = 0; j < 8; ++j) r[j] = 0;
  }
  *(ushort8*)(nbf + i) = r;
}

// ---------------------------------------------------------------- GEMM (bf16 MFMA)
// out[M,512] = [A0 | A1][*,KDIM] @ Bt^T + bias-term, f32 out.
// ROWCNT: bias-term = (cntBase[row+1]-cntBase[row]) * bias[col]  (he GEMM)
// else:   bias-term = bias[col] (+ bias2[col] if non-null)
// ADDOUT: += existing out
template <int KDIM, bool ADDOUT, bool ROWCNT>
__global__ __launch_bounds__(256, 2) void gemm_bf16(
    const unsigned short* __restrict__ A0, const unsigned short* __restrict__ A1,
    const unsigned short* __restrict__ Bt, const float* __restrict__ bias,
    const float* __restrict__ bias2, const int* __restrict__ cntBase,
    float* __restrict__ out, int M) {
  __shared__ unsigned short As[128 * 32];
  __shared__ unsigned short Bs[128 * 32];
  const int tid = threadIdx.x;
  const int lane = tid & 63;
  const int w = tid >> 6;
  const int wr = w >> 1, wc = w & 1;            // 2x2 waves -> 64x64 per wave
  const int row0 = blockIdx.y * 128;
  const int col0 = blockIdx.x * 128;

  f32x4 acc[4][4];
#pragma unroll
  for (int m = 0; m < 4; ++m)
#pragma unroll
    for (int n = 0; n < 4; ++n) acc[m][n] = f32x4{0.f, 0.f, 0.f, 0.f};

  const int c0 = w * 128 + lane;
  for (int kt = 0; kt < KDIM; kt += 32) {
#pragma unroll
    for (int j = 0; j < 2; ++j) {
      int c = c0 + j * 64;                      // 16B chunk: row = c>>2, k8 = (c&3)*8
      int r = c >> 2, k8 = (c & 3) << 3;
      const unsigned short* asrc;
      if (KDIM == 512 || kt < 512)
        asrc = A0 + (size_t)(row0 + r) * 512 + kt + k8;
      else
        asrc = A1 + (size_t)(row0 + r) * 512 + (kt - 512) + k8;
      g2l16(asrc, &As[c * 8]);
      g2l16(Bt + (size_t)(col0 + r) * KDIM + kt + k8, &Bs[c * 8]);
    }
    __syncthreads();
    bf16x8 a[4], b[4];
    const int r16 = lane & 15, kh = (lane >> 4) << 3;
#pragma unroll
    for (int m = 0; m < 4; ++m) a[m] = *(const bf16x8*)&As[(wr * 64 + m * 16 + r16) * 32 + kh];
#pragma unroll
    for (int n = 0; n < 4; ++n) b[n] = *(const bf16x8*)&Bs[(wc * 64 + n * 16 + r16) * 32 + kh];
#pragma unroll
    for (int m = 0; m < 4; ++m)
#pragma unroll
      for (int n = 0; n < 4; ++n)
        acc[m][n] = __builtin_amdgcn_mfma_f32_16x16x32_bf16(a[m], b[n], acc[m][n], 0, 0, 0);
    __syncthreads();
  }
  const int cgrp = (lane >> 4) * 4;
#pragma unroll
  for (int n = 0; n < 4; ++n) {
    int col = col0 + wc * 64 + n * 16 + (lane & 15);
    float bv = bias[col];
    if (!ROWCNT && bias2) bv += bias2[col];
#pragma unroll
    for (int m = 0; m < 4; ++m) {
#pragma unroll
      for (int r2 = 0; r2 < 4; ++r2) {
        int row = row0 + wr * 64 + m * 16 + cgrp + r2;
        if (row < M) {
          size_t idx = (size_t)row * CCH + col;
          float v = acc[m][n][r2];
          if (ROWCNT) v += (float)(cntBase[row + 1] - cntBase[row]) * bv;
          else v += bv;
          if (ADDOUT) v += out[idx];
          out[idx] = v;
        }
      }
    }
  }
}

// ---------------------------------------------------------------- LayerNorm (in-place, 1 wave / row)
__global__ void ln_kernel(float* __restrict__ y, const float* __restrict__ g,
                          const float* __restrict__ b, int nRows) {
  int row = blockIdx.x * 4 + (threadIdx.x >> 6);
  if (row >= nRows) return;
  int lane = threadIdx.x & 63;
  float* yr = y + (size_t)row * CCH;
  int d0 = lane * 8;
  float4 v0 = *(const float4*)(yr + d0);
  float4 v1 = *(const float4*)(yr + d0 + 4);
  float vv[8] = {v0.x, v0.y, v0.z, v0.w, v1.x, v1.y, v1.z, v1.w};
  float s = 0.f;
#pragma unroll
  for (int j = 0; j < 8; ++j) s += vv[j];
#pragma unroll
  for (int off = 1; off < 64; off <<= 1) s += __shfl_xor(s, off);
  float mu = s * (1.0f / 512.0f);
  float sq = 0.f;
#pragma unroll
  for (int j = 0; j < 8; ++j) { float d = vv[j] - mu; sq += d * d; }
#pragma unroll
  for (int off = 1; off < 64; off <<= 1) sq += __shfl_xor(sq, off);
  float rs = rsqrtf(sq * (1.0f / 512.0f) + 1e-5f);
  float4 g0 = *(const float4*)(g + d0), g1 = *(const float4*)(g + d0 + 4);
  float4 b0 = *(const float4*)(b + d0), b1 = *(const float4*)(b + d0 + 4);
  float gg[8] = {g0.x, g0.y, g0.z, g0.w, g1.x, g1.y, g1.z, g1.w};
  float bb[8] = {b0.x, b0.y, b0.z, b0.w, b1.x, b1.y, b1.z, b1.w};
  float o[8];
#pragma unroll
  for (int j = 0; j < 8; ++j) o[j] = gg[j] * (vv[j] - mu) * rs + bb[j];
  *(float4*)(yr + d0) = float4{o[0], o[1], o[2], o[3]};
  *(float4*)(yr + d0 + 4) = float4{o[4], o[5], o[6], o[7]};
}

// ---------------------------------------------------------------- host
extern "C" void kernel_launch(void* const* d_in, const int* in_sizes, int n_in,
                              void* d_out, int out_size, void* d_ws, size_t ws_size,
                              hipStream_t stream) {
  const float* x_a = (const float*)d_in[0];
  const float* x_b = (const float*)d_in[1];
  const int* nidx[2] = {(const int*)d_in[2], (const int*)d_in[4]};
  const int* hidx[2] = {(const int*)d_in[3], (const int*)d_in[5]};
  const float *kW[2], *kb[2], *qW[2], *qb[2], *aW[2], *ab[2], *sW[2], *sb[2], *lng[2], *lnb[2];
  for (int t = 0; t < 2; ++t) {
    int base = 7 + t * 10;
    kW[t] = (const float*)d_in[base + 0]; kb[t] = (const float*)d_in[base + 1];
    qW[t] = (const float*)d_in[base + 2]; qb[t] = (const float*)d_in[base + 3];
    aW[t] = (const float*)d_in[base + 4]; ab[t] = (const float*)d_in[base + 5];
    sW[t] = (const float*)d_in[base + 6]; sb[t] = (const float*)d_in[base + 7];
    lng[t] = (const float*)d_in[base + 8]; lnb[t] = (const float*)d_in[base + 9];
  }

  // ---------------- workspace layout
  const size_t SZ_XBF = (size_t)MPAD * CCH * 2;         // 41 MB
  const size_t SZ_WT_TYPE = (size_t)512 * 2048 * 2;     // 2 MB: k(512x512) q(512x512) comb(512x1024)
  const size_t SZ_HE = (size_t)NHE * CCH * 4;           // 33.5 MB
  const size_t SZ_BUFP = (size_t)MPAD * CCH * 4;        // 82 MB (Xagg bf16 / Q f32 / nbf)
  const size_t NBLK_ATTN = NNODE / 2;                   // 20000
  size_t off = 0;
  auto take = [&](size_t sz) { size_t o = off; off = (off + sz + 255) & ~(size_t)255; return o; };
  size_t o_xbf[2]; o_xbf[0] = take(SZ_XBF); o_xbf[1] = take(SZ_XBF);
  size_t o_wt = take(2 * SZ_WT_TYPE);
  size_t o_he = take(SZ_HE);
  size_t o_bufP = take(SZ_BUFP);
  size_t o_part = take(NBLK_ATTN * 8 * 4);
  size_t o_stats = take(256);
  size_t o_cnt = take((size_t)NNODE * 4);
  size_t o_baseH[2]; o_baseH[0] = take((NHE + 1) * 4); o_baseH[1] = take((NHE + 1) * 4);
  size_t o_baseN[2]; o_baseN[0] = take((NNODE + 1) * 4); o_baseN[1] = take((NNODE + 1) * 4);
  size_t o_nArrH[2]; o_nArrH[0] = take((size_t)NEDGE * 4); o_nArrH[1] = take((size_t)NEDGE * 4);
  size_t o_hArrN[2]; o_hArrN[0] = take((size_t)NEDGE * 4); o_hArrN[1] = take((size_t)NEDGE * 4);
  if (ws_size < off) return;

  char* ws = (char*)d_ws;
  unsigned short* xbf[2] = {(unsigned short*)(ws + o_xbf[0]), (unsigned short*)(ws + o_xbf[1])};
  auto wtK = [&](int t) { return (unsigned short*)(ws + o_wt + (size_t)t * SZ_WT_TYPE); };
  auto wtQ = [&](int t) { return wtK(t) + 512 * 512; };
  auto wtC = [&](int t) { return wtK(t) + 2 * 512 * 512; };  // combined [col][1024]: aW@0, sW@512
  float* he = (float*)(ws + o_he);
  float* bufP = (float*)(ws + o_bufP);                      // Q f32
  unsigned short* xagg = (unsigned short*)(ws + o_bufP);    // Xagg bf16 (before Q)
  unsigned short* nbf = (unsigned short*)(ws + o_bufP);     // node_out bf16 (after Q dead)
  float* partials = (float*)(ws + o_part);
  float* inv = (float*)(ws + o_stats);
  int* cnt = (int*)(ws + o_cnt);
  int* baseH[2] = {(int*)(ws + o_baseH[0]), (int*)(ws + o_baseH[1])};
  int* baseN[2] = {(int*)(ws + o_baseN[0]), (int*)(ws + o_baseN[1])};
  int* nArrH[2] = {(int*)(ws + o_nArrH[0]), (int*)(ws + o_nArrH[1])};
  int* hArrN[2] = {(int*)(ws + o_hArrN[0]), (int*)(ws + o_hArrN[1])};
  float* out = (float*)d_out;

  const long nValid = (long)NNODE * CCH, nTotal = (long)MPAD * CCH;
  const int cvtBlocks = (int)((nTotal / 8 + 255) / 256);
  const dim3 gemmGrid(4, MPAD / 128);
  const dim3 heGrid(4, NHE / 128);
  const int histBlocks = (NEDGE + 255) / 256;

  // ---------------- CSR builds (value arrays, no edge-id indirection)
  for (int t = 0; t < 2; ++t) {
    hipMemsetAsync(cnt, 0, (size_t)NNODE * 4, stream);
    hist_kernel<<<histBlocks, 256, 0, stream>>>(hidx[t], cnt, NEDGE);
    scan_kernel<<<1, 1024, 0, stream>>>(cnt, baseH[t], NHE);
    hipMemsetAsync(cnt, 0, (size_t)NNODE * 4, stream);
    fill_val<<<histBlocks, 256, 0, stream>>>(hidx[t], nidx[t], baseH[t], cnt, nArrH[t], NEDGE);
    hipMemsetAsync(cnt, 0, (size_t)NNODE * 4, stream);
    hist_kernel<<<histBlocks, 256, 0, stream>>>(nidx[t], cnt, NEDGE);
    scan_kernel<<<1, 1024, 0, stream>>>(cnt, baseN[t], NNODE);
    hipMemsetAsync(cnt, 0, (size_t)NNODE * 4, stream);
    fill_val<<<histBlocks, 256, 0, stream>>>(nidx[t], hidx[t], baseN[t], cnt, hArrN[t], NEDGE);
  }

  // ---------------- convert inputs / weights to bf16
  cvt_bf16_pad<<<cvtBlocks, 256, 0, stream>>>(x_a, xbf[0], nValid, nTotal);
  cvt_bf16_pad<<<cvtBlocks, 256, 0, stream>>>(x_b, xbf[1], nValid, nTotal);
  for (int t = 0; t < 2; ++t) {
    transpose_cvt<<<1024, 256, 0, stream>>>(kW[t], wtK(t), 512, 0);
    transpose_cvt<<<1024, 256, 0, stream>>>(qW[t], wtQ(t), 512, 0);
    transpose_cvt<<<1024, 256, 0, stream>>>(aW[t], wtC(t), 1024, 0);
    transpose_cvt<<<1024, 256, 0, stream>>>(sW[t], wtC(t), 1024, 512);
  }

  // ---------------- he = Xagg_a @ kW_a + cnt*kb_a, += Xagg_b @ kW_b + cnt*kb_b
  xagg_gather<false><<<NHE / 2, 256, 0, stream>>>(xbf[0], nArrH[0], baseH[0], xagg);
  gemm_bf16<512, false, true><<<heGrid, 256, 0, stream>>>(
      xagg, xagg, wtK(0), kb[0], nullptr, baseH[0], he, NHE);
  xagg_gather<false><<<NHE / 2, 256, 0, stream>>>(xbf[1], nArrH[1], baseH[1], xagg);
  gemm_bf16<512, true, true><<<heGrid, 256, 0, stream>>>(
      xagg, xagg, wtK(1), kb[1], nullptr, baseH[1], he, NHE);

  // ---------------- per-type attention + output
  for (int t = 0; t < 2; ++t) {
    float* dout_t = out + (size_t)t * NNODE * CCH;
    // Q projection (f32, into bufP)
    gemm_bf16<512, false, false><<<gemmGrid, 256, 0, stream>>>(
        xbf[t], xbf[t], wtQ(t), qb[t], nullptr, nullptr, bufP, NNODE);
    // fused attention: unnormalized node_out (scratch in dout_t) + per-block head sums
    fused_attn<<<(int)NBLK_ATTN, 256, 0, stream>>>(bufP, he, hArrN[t], baseN[t], dout_t, partials);
    reduce_partials<<<8, 256, 0, stream>>>(partials, inv, (int)NBLK_ATTN);
    // normalize + bf16 (nbf aliases bufP; Q dead now)
    norm_cvt<<<cvtBlocks, 256, 0, stream>>>(dout_t, inv, nbf);
    // fused: out = node_out @ aW + ab + x @ sW + sb   (K = 1024)
    gemm_bf16<1024, false, false><<<gemmGrid, 256, 0, stream>>>(
        nbf, xbf[t], wtC(t), ab[t], sb[t], nullptr, dout_t, NNODE);
    ln_kernel<<<(NNODE + 3) / 4, 256, 0, stream>>>(dout_t, lng[t], lnb[t], NNODE);
  }
}

// Round 4
// 961.068 us; speedup vs baseline: 4.2163x; 1.0418x over previous
//
#include <hip/hip_runtime.h>
#include <cstdint>

// Problem constants (match reference setup_inputs)
#define NNODE 40000
#define NEDGE 120000
#define NHE   16384
#define CCH   512
#define MPAD  40064   // 313 * 128, padded row count for GEMM A operands

typedef __attribute__((ext_vector_type(8))) short bf16x8;
typedef __attribute__((ext_vector_type(4))) float f32x4;
typedef __attribute__((ext_vector_type(8))) unsigned short ushort8;
typedef __attribute__((ext_vector_type(4))) unsigned short ushort4v;

// ---------------------------------------------------------------- helpers
__device__ __forceinline__ unsigned short f2bf(float f) {
  unsigned int u = __float_as_uint(f);
  u += 0x7FFFu + ((u >> 16) & 1u);   // round-to-nearest-even
  return (unsigned short)(u >> 16);
}
__device__ __forceinline__ float bf2f(unsigned short u) {
  return __uint_as_float((unsigned int)u << 16);
}

__device__ __forceinline__ void g2l16(const void* g, void* l) {
  // async global->LDS, 16B per lane. LDS dest must be wave-uniform base + lane*16.
  __builtin_amdgcn_global_load_lds(
      (const __attribute__((address_space(1))) unsigned int*)(uintptr_t)g,
      (__attribute__((address_space(3))) unsigned int*)(unsigned int)(uintptr_t)l,
      16, 0, 0);
}

// bijective XCD swizzle (m204): blocks with consecutive pid land on the same XCD
__device__ __forceinline__ int xcd_pid(int lin, int nwg) {
  int xcd = lin & 7, slot = lin >> 3;
  int q = nwg >> 3, r = nwg & 7;
  return ((xcd < r) ? (xcd * (q + 1)) : (r * (q + 1) + (xcd - r) * q)) + slot;
}

// ---------------------------------------------------------------- conversions
__global__ void cvt_bf16_pad(const float* __restrict__ in, unsigned short* __restrict__ out,
                             long nValid, long nTotal) {
  long i = ((long)blockIdx.x * blockDim.x + threadIdx.x) * 8;
  if (i >= nTotal) return;
  ushort8 r;
  if (i < nValid) {
    float4 a = *(const float4*)(in + i);
    float4 b = *(const float4*)(in + i + 4);
    r[0] = f2bf(a.x); r[1] = f2bf(a.y); r[2] = f2bf(a.z); r[3] = f2bf(a.w);
    r[4] = f2bf(b.x); r[5] = f2bf(b.y); r[6] = f2bf(b.z); r[7] = f2bf(b.w);
  } else {
    for (int j = 0; j < 8; ++j) r[j] = 0;
  }
  *(ushort8*)(out + i) = r;
}

// W [512][512] f32 row-major (y = x @ W) -> Wt [col][ldDst], k offset kOff, bf16
__global__ void transpose_cvt(const float* __restrict__ W, unsigned short* __restrict__ Wt,
                              int ldDst, int kOff) {
  int gid = blockIdx.x * 256 + threadIdx.x;     // 0 .. 512*512-1
  if (gid >= CCH * CCH) return;
  int i = gid >> 9, j = gid & 511;              // W[i][j]
  Wt[(size_t)j * ldDst + kOff + i] = f2bf(W[gid]);
}

// ---------------------------------------------------------------- CSR build
__global__ void hist_kernel(const int* __restrict__ idx, int* __restrict__ cnt, int E) {
  int e = blockIdx.x * 256 + threadIdx.x;
  if (e < E) atomicAdd(&cnt[idx[e]], 1);
}

// single-block exclusive scan, base[n] = total
__global__ void scan_kernel(const int* __restrict__ cnt, int* __restrict__ base, int n) {
  __shared__ int part[1024];
  int tid = threadIdx.x;
  int chunk = (n + 1023) >> 10;
  int lo = tid * chunk;
  int hi = lo + chunk; if (hi > n) hi = n;
  int s = 0;
  for (int i = lo; i < hi; ++i) s += cnt[i];
  part[tid] = s;
  __syncthreads();
  for (int off = 1; off < 1024; off <<= 1) {
    int v = (tid >= off) ? part[tid - off] : 0;
    __syncthreads();
    part[tid] += v;
    __syncthreads();
  }
  int excl = (tid == 0) ? 0 : part[tid - 1];
  for (int i = lo; i < hi; ++i) { base[i] = excl; excl += cnt[i]; }
  if (tid == 0) base[n] = part[1023];
}

// bucket by bidx[e], store val[e] into the slot (no edge-id indirection later)
__global__ void fill_val(const int* __restrict__ bidx, const int* __restrict__ val,
                         const int* __restrict__ base, int* __restrict__ cursor,
                         int* __restrict__ out, int E) {
  int e = blockIdx.x * 256 + threadIdx.x;
  if (e >= E) return;
  int b = bidx[e];
  int p = atomicAdd(&cursor[b], 1);
  out[base[b] + p] = val[e];
}

// ---------------------------------------------------------------- Xagg gather
// Xagg[h] (+)= sum over bucket of x_bf16[node]; written as bf16. 128 thr/row.
template <bool ADD>
__global__ void xagg_gather(const unsigned short* __restrict__ X, const int* __restrict__ nArr,
                            const int* __restrict__ base, unsigned short* __restrict__ Xagg) {
  int h = blockIdx.x * 2 + (threadIdx.x >> 7);
  if (h >= NHE) return;
  int sub = threadIdx.x & 127;
  int c4 = sub << 2;
  float ax = 0.f, ay = 0.f, az = 0.f, aw = 0.f;
  if (ADD) {
    ushort4v p = *(const ushort4v*)&Xagg[(size_t)h * CCH + c4];
    ax = bf2f(p[0]); ay = bf2f(p[1]); az = bf2f(p[2]); aw = bf2f(p[3]);
  }
  int b1 = base[h + 1];
  for (int i = base[h]; i < b1; ++i) {
    int n = nArr[i];
    ushort4v v = *(const ushort4v*)&X[(size_t)n * CCH + c4];
    ax += bf2f(v[0]); ay += bf2f(v[1]); az += bf2f(v[2]); aw += bf2f(v[3]);
  }
  ushort4v r = {f2bf(ax), f2bf(ay), f2bf(az), f2bf(aw)};
  *(ushort4v*)&Xagg[(size_t)h * CCH + c4] = r;
}

// ---------------------------------------------------------------- fused attention
// Per node: acc = sum_e exp(scale * q.he[h_e]) * he[h_e]  (UNNORMALIZED),
// per-head exp-sums -> per-block partials (no global atomics). Q is bf16.
__global__ void fused_attn(const unsigned short* __restrict__ Qb, const float* __restrict__ he,
                           const int* __restrict__ hArr, const int* __restrict__ base,
                           float* __restrict__ nout, float* __restrict__ partials) {
  __shared__ float lsum[8];
  if (threadIdx.x < 8) lsum[threadIdx.x] = 0.f;
  __syncthreads();
  int node = blockIdx.x * 2 + (threadIdx.x >> 7);
  int sub = threadIdx.x & 127;
  int c4 = sub << 2, h = sub >> 4;
  float psum = 0.f;
  if (node < NNODE) {
    ushort4v qv = *(const ushort4v*)&Qb[(size_t)node * CCH + c4];
    float qx = bf2f(qv[0]), qy = bf2f(qv[1]), qz = bf2f(qv[2]), qw = bf2f(qv[3]);
    float4 acc = {0.f, 0.f, 0.f, 0.f};
    int b1 = base[node + 1];
    for (int i = base[node]; i < b1; ++i) {
      int hid = hArr[i];
      float4 k = *(const float4*)&he[(size_t)hid * CCH + c4];
      float d = qx * k.x + qy * k.y + qz * k.z + qw * k.w;
      d += __shfl_xor(d, 1); d += __shfl_xor(d, 2);
      d += __shfl_xor(d, 4); d += __shfl_xor(d, 8);
      float a = __expf(d * 0.125f);   // scale = 1/sqrt(64); logits bounded, no max pass
      psum += a;
      acc.x += a * k.x; acc.y += a * k.y; acc.z += a * k.z; acc.w += a * k.w;
    }
    *(float4*)&nout[(size_t)node * CCH + c4] = acc;
  }
  if ((sub & 15) == 0) atomicAdd(&lsum[h], psum);
  __syncthreads();
  if (threadIdx.x < 8) partials[(size_t)blockIdx.x * 8 + threadIdx.x] = lsum[threadIdx.x];
}

// partials[nb][8] -> inv[8]; one block per head
__global__ void reduce_partials(const float* __restrict__ partials, float* __restrict__ inv, int nb) {
  __shared__ float ls[256];
  int h = blockIdx.x;
  float s = 0.f;
  for (int i = threadIdx.x; i < nb; i += 256) s += partials[(size_t)i * 8 + h];
  ls[threadIdx.x] = s;
  __syncthreads();
  for (int off = 128; off > 0; off >>= 1) {
    if (threadIdx.x < off) ls[threadIdx.x] += ls[threadIdx.x + off];
    __syncthreads();
  }
  if (threadIdx.x == 0) inv[h] = 1.0f / ls[0];
}

// nbf[n][c] = bf16( nout[n][c] * inv[head(c)] ), zero pad rows
__global__ void norm_cvt(const float* __restrict__ nout, const float* __restrict__ inv,
                         unsigned short* __restrict__ nbf) {
  long i = ((long)blockIdx.x * 256 + threadIdx.x) * 8;
  if (i >= (long)MPAD * CCH) return;
  ushort8 r;
  if (i < (long)NNODE * CCH) {
    int h = ((int)(i & 511)) >> 6;
    float iv = inv[h];
    float4 a = *(const float4*)(nout + i);
    float4 b = *(const float4*)(nout + i + 4);
    r[0] = f2bf(a.x * iv); r[1] = f2bf(a.y * iv); r[2] = f2bf(a.z * iv); r[3] = f2bf(a.w * iv);
    r[4] = f2bf(b.x * iv); r[5] = f2bf(b.y * iv); r[6] = f2bf(b.z * iv); r[7] = f2bf(b.w * iv);
  } else {
    for (int j = 0; j < 8; ++j) r[j] = 0;
  }
  *(ushort8*)(nbf + i) = r;
}

// ---------------------------------------------------------------- GEMM (bf16 MFMA)
// 1D grid, 4 col-blocks per row-panel, XCD-swizzled so the 4 col-blocks of a
// row-panel run on the same XCD (A panel fetched once into that XCD's L2).
// out[M,512] = [A0 | A1][*,KDIM] @ Bt^T + bias-term, f32 (or bf16) out.
// ROWCNT: bias-term = (cntBase[row+1]-cntBase[row]) * bias[col]  (he GEMM)
// else:   bias-term = bias[col] (+ bias2[col] if non-null)
// ADDOUT: += existing out.  OUTBF16: write bf16 to outb instead of f32 to out.
template <int KDIM, bool ADDOUT, bool ROWCNT, bool OUTBF16>
__global__ __launch_bounds__(256, 2) void gemm_bf16(
    const unsigned short* __restrict__ A0, const unsigned short* __restrict__ A1,
    const unsigned short* __restrict__ Bt, const float* __restrict__ bias,
    const float* __restrict__ bias2, const int* __restrict__ cntBase,
    float* __restrict__ out, unsigned short* __restrict__ outb, int M) {
  __shared__ unsigned short As[128 * 32];
  __shared__ unsigned short Bs[128 * 32];
  const int pid = xcd_pid(blockIdx.x, gridDim.x);
  const int row0 = (pid >> 2) * 128;
  const int col0 = (pid & 3) * 128;
  const int tid = threadIdx.x;
  const int lane = tid & 63;
  const int w = tid >> 6;
  const int wr = w >> 1, wc = w & 1;            // 2x2 waves -> 64x64 per wave

  f32x4 acc[4][4];
#pragma unroll
  for (int m = 0; m < 4; ++m)
#pragma unroll
    for (int n = 0; n < 4; ++n) acc[m][n] = f32x4{0.f, 0.f, 0.f, 0.f};

  const int c0 = w * 128 + lane;
  for (int kt = 0; kt < KDIM; kt += 32) {
#pragma unroll
    for (int j = 0; j < 2; ++j) {
      int c = c0 + j * 64;                      // 16B chunk: row = c>>2, k8 = (c&3)*8
      int r = c >> 2, k8 = (c & 3) << 3;
      const unsigned short* asrc;
      if (KDIM == 512 || kt < 512)
        asrc = A0 + (size_t)(row0 + r) * 512 + kt + k8;
      else
        asrc = A1 + (size_t)(row0 + r) * 512 + (kt - 512) + k8;
      g2l16(asrc, &As[c * 8]);
      g2l16(Bt + (size_t)(col0 + r) * KDIM + kt + k8, &Bs[c * 8]);
    }
    __syncthreads();
    bf16x8 a[4], b[4];
    const int r16 = lane & 15, kh = (lane >> 4) << 3;
#pragma unroll
    for (int m = 0; m < 4; ++m) a[m] = *(const bf16x8*)&As[(wr * 64 + m * 16 + r16) * 32 + kh];
#pragma unroll
    for (int n = 0; n < 4; ++n) b[n] = *(const bf16x8*)&Bs[(wc * 64 + n * 16 + r16) * 32 + kh];
#pragma unroll
    for (int m = 0; m < 4; ++m)
#pragma unroll
      for (int n = 0; n < 4; ++n)
        acc[m][n] = __builtin_amdgcn_mfma_f32_16x16x32_bf16(a[m], b[n], acc[m][n], 0, 0, 0);
    __syncthreads();
  }
  const int cgrp = (lane >> 4) * 4;
#pragma unroll
  for (int n = 0; n < 4; ++n) {
    int col = col0 + wc * 64 + n * 16 + (lane & 15);
    float bv = bias[col];
    if (!ROWCNT && bias2) bv += bias2[col];
#pragma unroll
    for (int m = 0; m < 4; ++m) {
#pragma unroll
      for (int r2 = 0; r2 < 4; ++r2) {
        int row = row0 + wr * 64 + m * 16 + cgrp + r2;
        if (row < M) {
          size_t idx = (size_t)row * CCH + col;
          float v = acc[m][n][r2];
          if (ROWCNT) v += (float)(cntBase[row + 1] - cntBase[row]) * bv;
          else v += bv;
          if (OUTBF16) {
            outb[idx] = f2bf(v);
          } else {
            if (ADDOUT) v += out[idx];
            out[idx] = v;
          }
        }
      }
    }
  }
}

// ---------------------------------------------------------------- LayerNorm (in-place, 1 wave / row)
__global__ void ln_kernel(float* __restrict__ y, const float* __restrict__ g,
                          const float* __restrict__ b, int nRows) {
  int row = blockIdx.x * 4 + (threadIdx.x >> 6);
  if (row >= nRows) return;
  int lane = threadIdx.x & 63;
  float* yr = y + (size_t)row * CCH;
  int d0 = lane * 8;
  float4 v0 = *(const float4*)(yr + d0);
  float4 v1 = *(const float4*)(yr + d0 + 4);
  float vv[8] = {v0.x, v0.y, v0.z, v0.w, v1.x, v1.y, v1.z, v1.w};
  float s = 0.f;
#pragma unroll
  for (int j = 0; j < 8; ++j) s += vv[j];
#pragma unroll
  for (int off = 1; off < 64; off <<= 1) s += __shfl_xor(s, off);
  float mu = s * (1.0f / 512.0f);
  float sq = 0.f;
#pragma unroll
  for (int j = 0; j < 8; ++j) { float d = vv[j] - mu; sq += d * d; }
#pragma unroll
  for (int off = 1; off < 64; off <<= 1) sq += __shfl_xor(sq, off);
  float rs = rsqrtf(sq * (1.0f / 512.0f) + 1e-5f);
  float4 g0 = *(const float4*)(g + d0), g1 = *(const float4*)(g + d0 + 4);
  float4 b0 = *(const float4*)(b + d0), b1 = *(const float4*)(b + d0 + 4);
  float gg[8] = {g0.x, g0.y, g0.z, g0.w, g1.x, g1.y, g1.z, g1.w};
  float bb[8] = {b0.x, b0.y, b0.z, b0.w, b1.x, b1.y, b1.z, b1.w};
  float o[8];
#pragma unroll
  for (int j = 0; j < 8; ++j) o[j] = gg[j] * (vv[j] - mu) * rs + bb[j];
  *(float4*)(yr + d0) = float4{o[0], o[1], o[2], o[3]};
  *(float4*)(yr + d0 + 4) = float4{o[4], o[5], o[6], o[7]};
}

// ---------------------------------------------------------------- host
extern "C" void kernel_launch(void* const* d_in, const int* in_sizes, int n_in,
                              void* d_out, int out_size, void* d_ws, size_t ws_size,
                              hipStream_t stream) {
  const float* x_a = (const float*)d_in[0];
  const float* x_b = (const float*)d_in[1];
  const int* nidx[2] = {(const int*)d_in[2], (const int*)d_in[4]};
  const int* hidx[2] = {(const int*)d_in[3], (const int*)d_in[5]};
  const float *kW[2], *kb[2], *qW[2], *qb[2], *aW[2], *ab[2], *sW[2], *sb[2], *lng[2], *lnb[2];
  for (int t = 0; t < 2; ++t) {
    int base = 7 + t * 10;
    kW[t] = (const float*)d_in[base + 0]; kb[t] = (const float*)d_in[base + 1];
    qW[t] = (const float*)d_in[base + 2]; qb[t] = (const float*)d_in[base + 3];
    aW[t] = (const float*)d_in[base + 4]; ab[t] = (const float*)d_in[base + 5];
    sW[t] = (const float*)d_in[base + 6]; sb[t] = (const float*)d_in[base + 7];
    lng[t] = (const float*)d_in[base + 8]; lnb[t] = (const float*)d_in[base + 9];
  }

  // ---------------- workspace layout
  const size_t SZ_XBF = (size_t)MPAD * CCH * 2;         // 41 MB
  const size_t SZ_WT_TYPE = (size_t)512 * 2048 * 2;     // 2 MB: k(512x512) q(512x512) comb(512x1024)
  const size_t SZ_HE = (size_t)NHE * CCH * 4;           // 33.5 MB
  const size_t SZ_BUFP = (size_t)MPAD * CCH * 4;        // 82 MB (Xagg bf16 / Qbf / nbf)
  const size_t NBLK_ATTN = NNODE / 2;                   // 20000
  size_t off = 0;
  auto take = [&](size_t sz) { size_t o = off; off = (off + sz + 255) & ~(size_t)255; return o; };
  size_t o_xbf[2]; o_xbf[0] = take(SZ_XBF); o_xbf[1] = take(SZ_XBF);
  size_t o_wt = take(2 * SZ_WT_TYPE);
  size_t o_he = take(SZ_HE);
  size_t o_bufP = take(SZ_BUFP);
  size_t o_part = take(NBLK_ATTN * 8 * 4);
  size_t o_stats = take(256);
  size_t o_cnt = take((size_t)NNODE * 4);
  size_t o_baseH[2]; o_baseH[0] = take((NHE + 1) * 4); o_baseH[1] = take((NHE + 1) * 4);
  size_t o_baseN[2]; o_baseN[0] = take((NNODE + 1) * 4); o_baseN[1] = take((NNODE + 1) * 4);
  size_t o_nArrH[2]; o_nArrH[0] = take((size_t)NEDGE * 4); o_nArrH[1] = take((size_t)NEDGE * 4);
  size_t o_hArrN[2]; o_hArrN[0] = take((size_t)NEDGE * 4); o_hArrN[1] = take((size_t)NEDGE * 4);
  if (ws_size < off) return;

  char* ws = (char*)d_ws;
  unsigned short* xbf[2] = {(unsigned short*)(ws + o_xbf[0]), (unsigned short*)(ws + o_xbf[1])};
  auto wtK = [&](int t) { return (unsigned short*)(ws + o_wt + (size_t)t * SZ_WT_TYPE); };
  auto wtQ = [&](int t) { return wtK(t) + 512 * 512; };
  auto wtC = [&](int t) { return wtK(t) + 2 * 512 * 512; };  // combined [col][1024]: aW@0, sW@512
  float* he = (float*)(ws + o_he);
  unsigned short* xagg = (unsigned short*)(ws + o_bufP);    // Xagg bf16
  unsigned short* qbf = (unsigned short*)(ws + o_bufP);     // Q bf16 (after Xagg dead)
  unsigned short* nbf = (unsigned short*)(ws + o_bufP);     // node_out bf16 (after Q dead)
  float* partials = (float*)(ws + o_part);
  float* inv = (float*)(ws + o_stats);
  int* cnt = (int*)(ws + o_cnt);
  int* baseH[2] = {(int*)(ws + o_baseH[0]), (int*)(ws + o_baseH[1])};
  int* baseN[2] = {(int*)(ws + o_baseN[0]), (int*)(ws + o_baseN[1])};
  int* nArrH[2] = {(int*)(ws + o_nArrH[0]), (int*)(ws + o_nArrH[1])};
  int* hArrN[2] = {(int*)(ws + o_hArrN[0]), (int*)(ws + o_hArrN[1])};
  float* out = (float*)d_out;

  const long nValid = (long)NNODE * CCH, nTotal = (long)MPAD * CCH;
  const int cvtBlocks = (int)((nTotal / 8 + 255) / 256);
  const int gemmBlocks = 4 * (MPAD / 128);   // 1252, 1D grid (XCD-swizzled in-kernel)
  const int heBlocks = 4 * (NHE / 128);      // 512
  const int histBlocks = (NEDGE + 255) / 256;

  // ---------------- CSR builds (value arrays, no edge-id indirection)
  for (int t = 0; t < 2; ++t) {
    hipMemsetAsync(cnt, 0, (size_t)NNODE * 4, stream);
    hist_kernel<<<histBlocks, 256, 0, stream>>>(hidx[t], cnt, NEDGE);
    scan_kernel<<<1, 1024, 0, stream>>>(cnt, baseH[t], NHE);
    hipMemsetAsync(cnt, 0, (size_t)NNODE * 4, stream);
    fill_val<<<histBlocks, 256, 0, stream>>>(hidx[t], nidx[t], baseH[t], cnt, nArrH[t], NEDGE);
    hipMemsetAsync(cnt, 0, (size_t)NNODE * 4, stream);
    hist_kernel<<<histBlocks, 256, 0, stream>>>(nidx[t], cnt, NEDGE);
    scan_kernel<<<1, 1024, 0, stream>>>(cnt, baseN[t], NNODE);
    hipMemsetAsync(cnt, 0, (size_t)NNODE * 4, stream);
    fill_val<<<histBlocks, 256, 0, stream>>>(nidx[t], hidx[t], baseN[t], cnt, hArrN[t], NEDGE);
  }

  // ---------------- convert inputs / weights to bf16
  cvt_bf16_pad<<<cvtBlocks, 256, 0, stream>>>(x_a, xbf[0], nValid, nTotal);
  cvt_bf16_pad<<<cvtBlocks, 256, 0, stream>>>(x_b, xbf[1], nValid, nTotal);
  for (int t = 0; t < 2; ++t) {
    transpose_cvt<<<1024, 256, 0, stream>>>(kW[t], wtK(t), 512, 0);
    transpose_cvt<<<1024, 256, 0, stream>>>(qW[t], wtQ(t), 512, 0);
    transpose_cvt<<<1024, 256, 0, stream>>>(aW[t], wtC(t), 1024, 0);
    transpose_cvt<<<1024, 256, 0, stream>>>(sW[t], wtC(t), 1024, 512);
  }

  // ---------------- he = Xagg_a @ kW_a + cnt*kb_a, += Xagg_b @ kW_b + cnt*kb_b
  xagg_gather<false><<<NHE / 2, 256, 0, stream>>>(xbf[0], nArrH[0], baseH[0], xagg);
  gemm_bf16<512, false, true, false><<<heBlocks, 256, 0, stream>>>(
      xagg, xagg, wtK(0), kb[0], nullptr, baseH[0], he, nullptr, NHE);
  xagg_gather<false><<<NHE / 2, 256, 0, stream>>>(xbf[1], nArrH[1], baseH[1], xagg);
  gemm_bf16<512, true, true, false><<<heBlocks, 256, 0, stream>>>(
      xagg, xagg, wtK(1), kb[1], nullptr, baseH[1], he, nullptr, NHE);

  // ---------------- per-type attention + output
  for (int t = 0; t < 2; ++t) {
    float* dout_t = out + (size_t)t * NNODE * CCH;
    // Q projection -> bf16 directly
    gemm_bf16<512, false, false, true><<<gemmBlocks, 256, 0, stream>>>(
        xbf[t], xbf[t], wtQ(t), qb[t], nullptr, nullptr, nullptr, qbf, NNODE);
    // fused attention: unnormalized node_out (scratch in dout_t) + per-block head sums
    fused_attn<<<(int)NBLK_ATTN, 256, 0, stream>>>(qbf, he, hArrN[t], baseN[t], dout_t, partials);
    reduce_partials<<<8, 256, 0, stream>>>(partials, inv, (int)NBLK_ATTN);
    // normalize + bf16 (nbf aliases qbf; Q dead now)
    norm_cvt<<<cvtBlocks, 256, 0, stream>>>(dout_t, inv, nbf);
    // fused: out = node_out @ aW + ab + x @ sW + sb   (K = 1024)
    gemm_bf16<1024, false, false, false><<<gemmBlocks, 256, 0, stream>>>(
        nbf, xbf[t], wtC(t), ab[t], sb[t], nullptr, dout_t, nullptr, NNODE);
    ln_kernel<<<(NNODE + 3) / 4, 256, 0, stream>>>(dout_t, lng[t], lnb[t], NNODE);
  }
}

// Round 5
// 899.829 us; speedup vs baseline: 4.5032x; 1.0681x over previous
//
#include <hip/hip_runtime.h>
#include <cstdint>

// Problem constants (match reference setup_inputs)
#define NNODE 40000
#define NEDGE 120000
#define NHE   16384
#define CCH   512
#define MPAD  40064   // 313 * 128, padded row count for GEMM A operands

typedef __attribute__((ext_vector_type(8))) short bf16x8;
typedef __attribute__((ext_vector_type(4))) float f32x4;
typedef __attribute__((ext_vector_type(8))) unsigned short ushort8;
typedef __attribute__((ext_vector_type(4))) unsigned short ushort4v;

// ---------------------------------------------------------------- helpers
__device__ __forceinline__ unsigned short f2bf(float f) {
  unsigned int u = __float_as_uint(f);
  u += 0x7FFFu + ((u >> 16) & 1u);   // round-to-nearest-even
  return (unsigned short)(u >> 16);
}
__device__ __forceinline__ float bf2f(unsigned short u) {
  return __uint_as_float((unsigned int)u << 16);
}

__device__ __forceinline__ void g2l16(const void* g, void* l) {
  // async global->LDS, 16B per lane. LDS dest must be wave-uniform base + lane*16.
  __builtin_amdgcn_global_load_lds(
      (const __attribute__((address_space(1))) unsigned int*)(uintptr_t)g,
      (__attribute__((address_space(3))) unsigned int*)(unsigned int)(uintptr_t)l,
      16, 0, 0);
}

// bijective XCD swizzle (m204): blocks with consecutive pid land on the same XCD
__device__ __forceinline__ int xcd_pid(int lin, int nwg) {
  int xcd = lin & 7, slot = lin >> 3;
  int q = nwg >> 3, r = nwg & 7;
  return ((xcd < r) ? (xcd * (q + 1)) : (r * (q + 1) + (xcd - r) * q)) + slot;
}

// ---------------------------------------------------------------- conversions
__global__ void cvt_bf16_pad(const float* __restrict__ in, unsigned short* __restrict__ out,
                             long nValid, long nTotal) {
  long i = ((long)blockIdx.x * blockDim.x + threadIdx.x) * 8;
  if (i >= nTotal) return;
  ushort8 r;
  if (i < nValid) {
    float4 a = *(const float4*)(in + i);
    float4 b = *(const float4*)(in + i + 4);
    r[0] = f2bf(a.x); r[1] = f2bf(a.y); r[2] = f2bf(a.z); r[3] = f2bf(a.w);
    r[4] = f2bf(b.x); r[5] = f2bf(b.y); r[6] = f2bf(b.z); r[7] = f2bf(b.w);
  } else {
    for (int j = 0; j < 8; ++j) r[j] = 0;
  }
  *(ushort8*)(out + i) = r;
}

// W [512][512] f32 row-major (y = x @ W) -> Wt [col][ldDst], k offset kOff, bf16
__global__ void transpose_cvt(const float* __restrict__ W, unsigned short* __restrict__ Wt,
                              int ldDst, int kOff) {
  int gid = blockIdx.x * 256 + threadIdx.x;     // 0 .. 512*512-1
  if (gid >= CCH * CCH) return;
  int i = gid >> 9, j = gid & 511;              // W[i][j]
  Wt[(size_t)j * ldDst + kOff + i] = f2bf(W[gid]);
}

// same, but scale row k of W by inv[k>>6] (folds softmax denominator into aW)
__global__ void transpose_cvt_scale(const float* __restrict__ W, const float* __restrict__ inv,
                                    unsigned short* __restrict__ Wt, int ldDst) {
  int gid = blockIdx.x * 256 + threadIdx.x;
  if (gid >= CCH * CCH) return;
  int i = gid >> 9, j = gid & 511;              // W[i][j], i is the k index
  Wt[(size_t)j * ldDst + i] = f2bf(W[gid] * inv[i >> 6]);
}

// ---------------------------------------------------------------- CSR build
__global__ void hist_kernel(const int* __restrict__ idx, int* __restrict__ cnt, int E) {
  int e = blockIdx.x * 256 + threadIdx.x;
  if (e < E) atomicAdd(&cnt[idx[e]], 1);
}

// single-block exclusive scan, base[n] = total; also zeroes cur[0..n)
__global__ void scan_kernel(const int* __restrict__ cnt, int* __restrict__ base,
                            int* __restrict__ cur, int n) {
  __shared__ int part[1024];
  int tid = threadIdx.x;
  int chunk = (n + 1023) >> 10;
  int lo = tid * chunk;
  int hi = lo + chunk; if (hi > n) hi = n;
  int s = 0;
  for (int i = lo; i < hi; ++i) s += cnt[i];
  part[tid] = s;
  __syncthreads();
  for (int off = 1; off < 1024; off <<= 1) {
    int v = (tid >= off) ? part[tid - off] : 0;
    __syncthreads();
    part[tid] += v;
    __syncthreads();
  }
  int excl = (tid == 0) ? 0 : part[tid - 1];
  for (int i = lo; i < hi; ++i) { base[i] = excl; excl += cnt[i]; cur[i] = 0; }
  if (tid == 0) base[n] = part[1023];
}

// bucket by bidx[e], store val[e] into the slot (no edge-id indirection later)
__global__ void fill_val(const int* __restrict__ bidx, const int* __restrict__ val,
                         const int* __restrict__ base, int* __restrict__ cursor,
                         int* __restrict__ out, int E) {
  int e = blockIdx.x * 256 + threadIdx.x;
  if (e >= E) return;
  int b = bidx[e];
  int p = atomicAdd(&cursor[b], 1);
  out[base[b] + p] = val[e];
}

// ---------------------------------------------------------------- Xagg gather
// Xagg[h] = sum over bucket of x_bf16[node]; written as bf16. 128 thr/row.
__global__ void xagg_gather(const unsigned short* __restrict__ X, const int* __restrict__ nArr,
                            const int* __restrict__ base, unsigned short* __restrict__ Xagg) {
  int h = blockIdx.x * 2 + (threadIdx.x >> 7);
  if (h >= NHE) return;
  int sub = threadIdx.x & 127;
  int c4 = sub << 2;
  float ax = 0.f, ay = 0.f, az = 0.f, aw = 0.f;
  int b1 = base[h + 1];
  for (int i = base[h]; i < b1; ++i) {
    int n = nArr[i];
    ushort4v v = *(const ushort4v*)&X[(size_t)n * CCH + c4];
    ax += bf2f(v[0]); ay += bf2f(v[1]); az += bf2f(v[2]); aw += bf2f(v[3]);
  }
  ushort4v r = {f2bf(ax), f2bf(ay), f2bf(az), f2bf(aw)};
  *(ushort4v*)&Xagg[(size_t)h * CCH + c4] = r;
}

// ---------------------------------------------------------------- fused attention
// One wave per node. acc = sum_e exp(scale * q.he[h_e]) * he[h_e] (UNNORMALIZED),
// written directly as bf16 (normalization folded into aW later).
// Per-head exp-sums -> per-block partials (no global atomics).
__global__ void fused_attn(const unsigned short* __restrict__ Qb,
                           const unsigned short* __restrict__ heb,
                           const int* __restrict__ hArr, const int* __restrict__ base,
                           unsigned short* __restrict__ nbf, float* __restrict__ partials) {
  __shared__ float lsum[8];
  if (threadIdx.x < 8) lsum[threadIdx.x] = 0.f;
  __syncthreads();
  int node = blockIdx.x * 4 + (threadIdx.x >> 6);   // grid covers MPAD exactly
  int lane = threadIdx.x & 63;
  int d0 = lane << 3;                               // 8 channels per lane, head = lane>>3
  float acc[8] = {0.f, 0.f, 0.f, 0.f, 0.f, 0.f, 0.f, 0.f};
  float psum = 0.f;
  if (node < NNODE) {
    ushort8 qv = *(const ushort8*)&Qb[(size_t)node * CCH + d0];
    float q[8];
#pragma unroll
    for (int j = 0; j < 8; ++j) q[j] = bf2f(qv[j]);
    int b1 = base[node + 1];
    for (int i = base[node]; i < b1; ++i) {
      int hid = hArr[i];
      ushort8 kv = *(const ushort8*)&heb[(size_t)hid * CCH + d0];
      float k[8];
#pragma unroll
      for (int j = 0; j < 8; ++j) k[j] = bf2f(kv[j]);
      float d = q[0] * k[0] + q[1] * k[1] + q[2] * k[2] + q[3] * k[3] +
                q[4] * k[4] + q[5] * k[5] + q[6] * k[6] + q[7] * k[7];
      d += __shfl_xor(d, 1); d += __shfl_xor(d, 2); d += __shfl_xor(d, 4);
      float a = __expf(d * 0.125f);   // scale = 1/sqrt(64); logits bounded, no max pass
      psum += a;
#pragma unroll
      for (int j = 0; j < 8; ++j) acc[j] += a * k[j];
    }
  }
  ushort8 r;
#pragma unroll
  for (int j = 0; j < 8; ++j) r[j] = f2bf(acc[j]);
  *(ushort8*)&nbf[(size_t)node * CCH + d0] = r;     // pad rows get zeros
  if ((lane & 7) == 0) atomicAdd(&lsum[lane >> 3], psum);
  __syncthreads();
  if (threadIdx.x < 8) partials[(size_t)blockIdx.x * 8 + threadIdx.x] = lsum[threadIdx.x];
}

// partials[nb][8] -> inv[8]; one block per head
__global__ void reduce_partials(const float* __restrict__ partials, float* __restrict__ inv, int nb) {
  __shared__ float ls[256];
  int h = blockIdx.x;
  float s = 0.f;
  for (int i = threadIdx.x; i < nb; i += 256) s += partials[(size_t)i * 8 + h];
  ls[threadIdx.x] = s;
  __syncthreads();
  for (int off = 128; off > 0; off >>= 1) {
    if (threadIdx.x < off) ls[threadIdx.x] += ls[threadIdx.x + off];
    __syncthreads();
  }
  if (threadIdx.x == 0) inv[h] = 1.0f / ls[0];
}

// ---------------------------------------------------------------- GEMM (bf16 MFMA)
// 1D grid, 4 col-blocks per row-panel, XCD-swizzled so the 4 col-blocks of a
// row-panel run on the same XCD (A panel fetched once into that XCD's L2).
// out[M,512] = [A0 | A1][*,KDIM] @ Bt^T + bias-term, f32 (or bf16) out.
// ROWCNT: bias-term = (cntA[row+1]-cntA[row])*bias[col] + (cntB[row+1]-cntB[row])*bias2[col]
// else:   bias-term = bias[col] (+ bias2[col] if non-null)
// ADDOUT: += existing out.  OUTBF16: write bf16 to outb instead of f32 to out.
template <int KDIM, bool ADDOUT, bool ROWCNT, bool OUTBF16>
__global__ __launch_bounds__(256, 2) void gemm_bf16(
    const unsigned short* __restrict__ A0, const unsigned short* __restrict__ A1,
    const unsigned short* __restrict__ Bt, const float* __restrict__ bias,
    const float* __restrict__ bias2, const int* __restrict__ cntA,
    const int* __restrict__ cntB,
    float* __restrict__ out, unsigned short* __restrict__ outb, int M) {
  __shared__ unsigned short As[128 * 32];
  __shared__ unsigned short Bs[128 * 32];
  const int pid = xcd_pid(blockIdx.x, gridDim.x);
  const int row0 = (pid >> 2) * 128;
  const int col0 = (pid & 3) * 128;
  const int tid = threadIdx.x;
  const int lane = tid & 63;
  const int w = tid >> 6;
  const int wr = w >> 1, wc = w & 1;            // 2x2 waves -> 64x64 per wave

  f32x4 acc[4][4];
#pragma unroll
  for (int m = 0; m < 4; ++m)
#pragma unroll
    for (int n = 0; n < 4; ++n) acc[m][n] = f32x4{0.f, 0.f, 0.f, 0.f};

  const int c0 = w * 128 + lane;
  for (int kt = 0; kt < KDIM; kt += 32) {
#pragma unroll
    for (int j = 0; j < 2; ++j) {
      int c = c0 + j * 64;                      // 16B chunk: row = c>>2, k8 = (c&3)*8
      int r = c >> 2, k8 = (c & 3) << 3;
      const unsigned short* asrc;
      if (KDIM == 512 || kt < 512)
        asrc = A0 + (size_t)(row0 + r) * 512 + kt + k8;
      else
        asrc = A1 + (size_t)(row0 + r) * 512 + (kt - 512) + k8;
      g2l16(asrc, &As[c * 8]);
      g2l16(Bt + (size_t)(col0 + r) * KDIM + kt + k8, &Bs[c * 8]);
    }
    __syncthreads();
    bf16x8 a[4], b[4];
    const int r16 = lane & 15, kh = (lane >> 4) << 3;
#pragma unroll
    for (int m = 0; m < 4; ++m) a[m] = *(const bf16x8*)&As[(wr * 64 + m * 16 + r16) * 32 + kh];
#pragma unroll
    for (int n = 0; n < 4; ++n) b[n] = *(const bf16x8*)&Bs[(wc * 64 + n * 16 + r16) * 32 + kh];
#pragma unroll
    for (int m = 0; m < 4; ++m)
#pragma unroll
      for (int n = 0; n < 4; ++n)
        acc[m][n] = __builtin_amdgcn_mfma_f32_16x16x32_bf16(a[m], b[n], acc[m][n], 0, 0, 0);
    __syncthreads();
  }
  const int cgrp = (lane >> 4) * 4;
#pragma unroll
  for (int n = 0; n < 4; ++n) {
    int col = col0 + wc * 64 + n * 16 + (lane & 15);
    float bv = bias[col];
    float bv2 = 0.f;
    if (ROWCNT) bv2 = bias2[col];
    else if (bias2) bv += bias2[col];
#pragma unroll
    for (int m = 0; m < 4; ++m) {
#pragma unroll
      for (int r2 = 0; r2 < 4; ++r2) {
        int row = row0 + wr * 64 + m * 16 + cgrp + r2;
        if (row < M) {
          size_t idx = (size_t)row * CCH + col;
          float v = acc[m][n][r2];
          if (ROWCNT)
            v += (float)(cntA[row + 1] - cntA[row]) * bv +
                 (float)(cntB[row + 1] - cntB[row]) * bv2;
          else v += bv;
          if (OUTBF16) {
            outb[idx] = f2bf(v);
          } else {
            if (ADDOUT) v += out[idx];
            out[idx] = v;
          }
        }
      }
    }
  }
}

// ---------------------------------------------------------------- LayerNorm (in-place, 1 wave / row)
__global__ void ln_kernel(float* __restrict__ y, const float* __restrict__ g,
                          const float* __restrict__ b, int nRows) {
  int row = blockIdx.x * 4 + (threadIdx.x >> 6);
  if (row >= nRows) return;
  int lane = threadIdx.x & 63;
  float* yr = y + (size_t)row * CCH;
  int d0 = lane * 8;
  float4 v0 = *(const float4*)(yr + d0);
  float4 v1 = *(const float4*)(yr + d0 + 4);
  float vv[8] = {v0.x, v0.y, v0.z, v0.w, v1.x, v1.y, v1.z, v1.w};
  float s = 0.f;
#pragma unroll
  for (int j = 0; j < 8; ++j) s += vv[j];
#pragma unroll
  for (int off = 1; off < 64; off <<= 1) s += __shfl_xor(s, off);
  float mu = s * (1.0f / 512.0f);
  float sq = 0.f;
#pragma unroll
  for (int j = 0; j < 8; ++j) { float d = vv[j] - mu; sq += d * d; }
#pragma unroll
  for (int off = 1; off < 64; off <<= 1) sq += __shfl_xor(sq, off);
  float rs = rsqrtf(sq * (1.0f / 512.0f) + 1e-5f);
  float4 g0 = *(const float4*)(g + d0), g1 = *(const float4*)(g + d0 + 4);
  float4 b0 = *(const float4*)(b + d0), b1 = *(const float4*)(b + d0 + 4);
  float gg[8] = {g0.x, g0.y, g0.z, g0.w, g1.x, g1.y, g1.z, g1.w};
  float bb[8] = {b0.x, b0.y, b0.z, b0.w, b1.x, b1.y, b1.z, b1.w};
  float o[8];
#pragma unroll
  for (int j = 0; j < 8; ++j) o[j] = gg[j] * (vv[j] - mu) * rs + bb[j];
  *(float4*)(yr + d0) = float4{o[0], o[1], o[2], o[3]};
  *(float4*)(yr + d0 + 4) = float4{o[4], o[5], o[6], o[7]};
}

// ---------------------------------------------------------------- host
extern "C" void kernel_launch(void* const* d_in, const int* in_sizes, int n_in,
                              void* d_out, int out_size, void* d_ws, size_t ws_size,
                              hipStream_t stream) {
  const float* x_a = (const float*)d_in[0];
  const float* x_b = (const float*)d_in[1];
  const int* nidx[2] = {(const int*)d_in[2], (const int*)d_in[4]};
  const int* hidx[2] = {(const int*)d_in[3], (const int*)d_in[5]};
  const float *kW[2], *kb[2], *qW[2], *qb[2], *aW[2], *ab[2], *sW[2], *sb[2], *lng[2], *lnb[2];
  for (int t = 0; t < 2; ++t) {
    int base = 7 + t * 10;
    kW[t] = (const float*)d_in[base + 0]; kb[t] = (const float*)d_in[base + 1];
    qW[t] = (const float*)d_in[base + 2]; qb[t] = (const float*)d_in[base + 3];
    aW[t] = (const float*)d_in[base + 4]; ab[t] = (const float*)d_in[base + 5];
    sW[t] = (const float*)d_in[base + 6]; sb[t] = (const float*)d_in[base + 7];
    lng[t] = (const float*)d_in[base + 8]; lnb[t] = (const float*)d_in[base + 9];
  }

  // ---------------- workspace layout
  const size_t SZ_XBF = (size_t)MPAD * CCH * 2;         // 41 MB
  const size_t SZ_XAGG = (size_t)NHE * CCH * 2;         // 16.8 MB
  const size_t SZ_HEB = (size_t)NHE * CCH * 2;          // 16.8 MB
  const size_t NBLK_ATTN = MPAD / 4;                    // 10016
  size_t off = 0;
  auto take = [&](size_t sz) { size_t o = off; off = (off + sz + 255) & ~(size_t)255; return o; };
  size_t o_xbf[2]; o_xbf[0] = take(SZ_XBF); o_xbf[1] = take(SZ_XBF);
  size_t o_wtQ[2]; o_wtQ[0] = take((size_t)512 * 512 * 2); o_wtQ[1] = take((size_t)512 * 512 * 2);
  size_t o_wtC[2]; o_wtC[0] = take((size_t)512 * 1024 * 2); o_wtC[1] = take((size_t)512 * 1024 * 2);
  size_t o_wtHE = take((size_t)512 * 1024 * 2);
  size_t o_heb = take(SZ_HEB);
  size_t o_bufP = take(SZ_XBF);                         // xagg_a+xagg_b, later qbf
  size_t o_nbf = take(SZ_XBF);
  size_t o_part = take(NBLK_ATTN * 8 * 4);
  size_t o_stats = take(256);
  size_t o_cnt = take((size_t)NNODE * 4);
  size_t o_cur = take((size_t)NNODE * 4);
  size_t o_baseH[2]; o_baseH[0] = take((NHE + 1) * 4); o_baseH[1] = take((NHE + 1) * 4);
  size_t o_baseN[2]; o_baseN[0] = take((NNODE + 1) * 4); o_baseN[1] = take((NNODE + 1) * 4);
  size_t o_nArrH[2]; o_nArrH[0] = take((size_t)NEDGE * 4); o_nArrH[1] = take((size_t)NEDGE * 4);
  size_t o_hArrN[2]; o_hArrN[0] = take((size_t)NEDGE * 4); o_hArrN[1] = take((size_t)NEDGE * 4);
  if (ws_size < off) return;

  char* ws = (char*)d_ws;
  unsigned short* xbf[2] = {(unsigned short*)(ws + o_xbf[0]), (unsigned short*)(ws + o_xbf[1])};
  unsigned short* wtQ[2] = {(unsigned short*)(ws + o_wtQ[0]), (unsigned short*)(ws + o_wtQ[1])};
  unsigned short* wtC[2] = {(unsigned short*)(ws + o_wtC[0]), (unsigned short*)(ws + o_wtC[1])};
  unsigned short* wtHE = (unsigned short*)(ws + o_wtHE);
  unsigned short* heb = (unsigned short*)(ws + o_heb);
  unsigned short* xaggA = (unsigned short*)(ws + o_bufP);
  unsigned short* xaggB = xaggA + (size_t)NHE * CCH;
  unsigned short* qbf = (unsigned short*)(ws + o_bufP);     // aliases xagg (dead after he GEMM)
  unsigned short* nbf = (unsigned short*)(ws + o_nbf);
  float* partials = (float*)(ws + o_part);
  float* inv = (float*)(ws + o_stats);
  int* cnt = (int*)(ws + o_cnt);
  int* cur = (int*)(ws + o_cur);
  int* baseH[2] = {(int*)(ws + o_baseH[0]), (int*)(ws + o_baseH[1])};
  int* baseN[2] = {(int*)(ws + o_baseN[0]), (int*)(ws + o_baseN[1])};
  int* nArrH[2] = {(int*)(ws + o_nArrH[0]), (int*)(ws + o_nArrH[1])};
  int* hArrN[2] = {(int*)(ws + o_hArrN[0]), (int*)(ws + o_hArrN[1])};
  float* out = (float*)d_out;

  const long nValid = (long)NNODE * CCH, nTotal = (long)MPAD * CCH;
  const int cvtBlocks = (int)((nTotal / 8 + 255) / 256);
  const int gemmBlocks = 4 * (MPAD / 128);   // 1252, 1D grid (XCD-swizzled in-kernel)
  const int heBlocks = 4 * (NHE / 128);      // 512
  const int histBlocks = (NEDGE + 255) / 256;

  // ---------------- CSR builds (value arrays, no edge-id indirection)
  for (int t = 0; t < 2; ++t) {
    hipMemsetAsync(cnt, 0, (size_t)NNODE * 4, stream);
    hist_kernel<<<histBlocks, 256, 0, stream>>>(hidx[t], cnt, NEDGE);
    scan_kernel<<<1, 1024, 0, stream>>>(cnt, baseH[t], cur, NHE);
    fill_val<<<histBlocks, 256, 0, stream>>>(hidx[t], nidx[t], baseH[t], cur, nArrH[t], NEDGE);
    hipMemsetAsync(cnt, 0, (size_t)NNODE * 4, stream);
    hist_kernel<<<histBlocks, 256, 0, stream>>>(nidx[t], cnt, NEDGE);
    scan_kernel<<<1, 1024, 0, stream>>>(cnt, baseN[t], cur, NNODE);
    fill_val<<<histBlocks, 256, 0, stream>>>(nidx[t], hidx[t], baseN[t], cur, hArrN[t], NEDGE);
  }

  // ---------------- convert inputs / weights to bf16
  cvt_bf16_pad<<<cvtBlocks, 256, 0, stream>>>(x_a, xbf[0], nValid, nTotal);
  cvt_bf16_pad<<<cvtBlocks, 256, 0, stream>>>(x_b, xbf[1], nValid, nTotal);
  for (int t = 0; t < 2; ++t) {
    transpose_cvt<<<1024, 256, 0, stream>>>(qW[t], wtQ[t], 512, 0);
    transpose_cvt<<<1024, 256, 0, stream>>>(sW[t], wtC[t], 1024, 512);  // aW half filled later
    transpose_cvt<<<1024, 256, 0, stream>>>(kW[t], wtHE, 1024, t * 512);
  }

  // ---------------- he = [Xagg_a|Xagg_b] @ [kW_a;kW_b] + cntA*kb_a + cntB*kb_b  (bf16)
  xagg_gather<<<NHE / 2, 256, 0, stream>>>(xbf[0], nArrH[0], baseH[0], xaggA);
  xagg_gather<<<NHE / 2, 256, 0, stream>>>(xbf[1], nArrH[1], baseH[1], xaggB);
  gemm_bf16<1024, false, true, true><<<heBlocks, 256, 0, stream>>>(
      xaggA, xaggB, wtHE, kb[0], kb[1], baseH[0], baseH[1], nullptr, heb, NHE);

  // ---------------- per-type attention + output
  for (int t = 0; t < 2; ++t) {
    float* dout_t = out + (size_t)t * NNODE * CCH;
    // Q projection -> bf16 (qbf aliases xagg region; xagg dead after he GEMM)
    gemm_bf16<512, false, false, true><<<gemmBlocks, 256, 0, stream>>>(
        xbf[t], xbf[t], wtQ[t], qb[t], nullptr, nullptr, nullptr, nullptr, qbf, NNODE);
    // fused attention: unnormalized bf16 node_out + per-block head exp-sums
    fused_attn<<<(int)NBLK_ATTN, 256, 0, stream>>>(qbf, heb, hArrN[t], baseN[t], nbf, partials);
    reduce_partials<<<8, 256, 0, stream>>>(partials, inv, (int)NBLK_ATTN);
    // fold softmax denominator into aW (rows scaled by inv[head])
    transpose_cvt_scale<<<1024, 256, 0, stream>>>(aW[t], inv, wtC[t], 1024);
    // fused: out = node_out_unnorm @ (inv*aW) + ab + x @ sW + sb   (K = 1024)
    gemm_bf16<1024, false, false, false><<<gemmBlocks, 256, 0, stream>>>(
        nbf, xbf[t], wtC[t], ab[t], sb[t], nullptr, nullptr, dout_t, nullptr, NNODE);
    ln_kernel<<<(NNODE + 3) / 4, 256, 0, stream>>>(dout_t, lng[t], lnb[t], NNODE);
  }
}

// Round 6
// 720.093 us; speedup vs baseline: 5.6272x; 1.2496x over previous
//
#include <hip/hip_runtime.h>
#include <cstdint>

// Problem constants (match reference setup_inputs)
#define NNODE 40000
#define NEDGE 120000
#define NHE   16384
#define CCH   512
#define MPAD  40064   // 313 * 128, padded row count for GEMM A operands

typedef __attribute__((ext_vector_type(8))) short bf16x8;
typedef __attribute__((ext_vector_type(4))) float f32x4;
typedef __attribute__((ext_vector_type(8))) unsigned short ushort8;
typedef __attribute__((ext_vector_type(4))) unsigned short ushort4v;

// ---------------------------------------------------------------- helpers
__device__ __forceinline__ unsigned short f2bf(float f) {
  unsigned int u = __float_as_uint(f);
  u += 0x7FFFu + ((u >> 16) & 1u);   // round-to-nearest-even
  return (unsigned short)(u >> 16);
}
__device__ __forceinline__ float bf2f(unsigned short u) {
  return __uint_as_float((unsigned int)u << 16);
}

__device__ __forceinline__ void g2l16(const void* g, void* l) {
  // async global->LDS, 16B per lane. LDS dest must be wave-uniform base + lane*16.
  __builtin_amdgcn_global_load_lds(
      (const __attribute__((address_space(1))) unsigned int*)(uintptr_t)g,
      (__attribute__((address_space(3))) unsigned int*)(unsigned int)(uintptr_t)l,
      16, 0, 0);
}

// bijective XCD swizzle (m204): blocks with consecutive pid land on the same XCD
__device__ __forceinline__ int xcd_pid(int lin, int nwg) {
  int xcd = lin & 7, slot = lin >> 3;
  int q = nwg >> 3, r = nwg & 7;
  return ((xcd < r) ? (xcd * (q + 1)) : (r * (q + 1) + (xcd - r) * q)) + slot;
}

// ---------------------------------------------------------------- conversions
__global__ void cvt_bf16_pad(const float* __restrict__ in, unsigned short* __restrict__ out,
                             long nValid, long nTotal) {
  long i = ((long)blockIdx.x * blockDim.x + threadIdx.x) * 8;
  if (i >= nTotal) return;
  ushort8 r;
  if (i < nValid) {
    float4 a = *(const float4*)(in + i);
    float4 b = *(const float4*)(in + i + 4);
    r[0] = f2bf(a.x); r[1] = f2bf(a.y); r[2] = f2bf(a.z); r[3] = f2bf(a.w);
    r[4] = f2bf(b.x); r[5] = f2bf(b.y); r[6] = f2bf(b.z); r[7] = f2bf(b.w);
  } else {
    for (int j = 0; j < 8; ++j) r[j] = 0;
  }
  *(ushort8*)(out + i) = r;
}

// W [512][512] f32 row-major (y = x @ W) -> Wt [col][ldDst], k offset kOff, bf16
__global__ void transpose_cvt(const float* __restrict__ W, unsigned short* __restrict__ Wt,
                              int ldDst, int kOff) {
  int gid = blockIdx.x * 256 + threadIdx.x;     // 0 .. 512*512-1
  if (gid >= CCH * CCH) return;
  int i = gid >> 9, j = gid & 511;              // W[i][j]
  Wt[(size_t)j * ldDst + kOff + i] = f2bf(W[gid]);
}

// same, but scale row k of W by inv[k>>6] (folds softmax denominator into aW)
__global__ void transpose_cvt_scale(const float* __restrict__ W, const float* __restrict__ inv,
                                    unsigned short* __restrict__ Wt, int ldDst) {
  int gid = blockIdx.x * 256 + threadIdx.x;
  if (gid >= CCH * CCH) return;
  int i = gid >> 9, j = gid & 511;              // W[i][j], i is the k index
  Wt[(size_t)j * ldDst + i] = f2bf(W[gid] * inv[i >> 6]);
}

// ---------------------------------------------------------------- CSR build (collapsed)
// one pass builds all 4 histograms
__global__ void hist4(const int* __restrict__ hA, const int* __restrict__ hB,
                      const int* __restrict__ nA, const int* __restrict__ nB,
                      int* __restrict__ cntHA, int* __restrict__ cntHB,
                      int* __restrict__ cntNA, int* __restrict__ cntNB, int E) {
  int e = blockIdx.x * 256 + threadIdx.x;
  if (e >= E) return;
  atomicAdd(&cntHA[hA[e]], 1);
  atomicAdd(&cntHB[hB[e]], 1);
  atomicAdd(&cntNA[nA[e]], 1);
  atomicAdd(&cntNB[nB[e]], 1);
}

// 4 independent single-block exclusive scans (block b handles array b);
// zeroes cnt in place (becomes the fill cursor), writes base[n]=total
__global__ void scan4(int* __restrict__ c0, int* __restrict__ b0, int n0,
                      int* __restrict__ c1, int* __restrict__ b1, int n1,
                      int* __restrict__ c2, int* __restrict__ b2, int n2,
                      int* __restrict__ c3, int* __restrict__ b3, int n3) {
  __shared__ int part[1024];
  int* cnt; int* base; int n;
  if (blockIdx.x == 0) { cnt = c0; base = b0; n = n0; }
  else if (blockIdx.x == 1) { cnt = c1; base = b1; n = n1; }
  else if (blockIdx.x == 2) { cnt = c2; base = b2; n = n2; }
  else { cnt = c3; base = b3; n = n3; }
  int tid = threadIdx.x;
  int chunk = (n + 1023) >> 10;
  int lo = tid * chunk;
  int hi = lo + chunk; if (hi > n) hi = n;
  int s = 0;
  for (int i = lo; i < hi; ++i) s += cnt[i];
  part[tid] = s;
  __syncthreads();
  for (int off = 1; off < 1024; off <<= 1) {
    int v = (tid >= off) ? part[tid - off] : 0;
    __syncthreads();
    part[tid] += v;
    __syncthreads();
  }
  int excl = (tid == 0) ? 0 : part[tid - 1];
  for (int i = lo; i < hi; ++i) { base[i] = excl; excl += cnt[i]; cnt[i] = 0; }
  if (tid == 0) base[n] = part[1023];
}

// fills all 4 CSR value arrays (he-CSR stores node ids; node-CSR stores he ids)
__global__ void fill4(const int* __restrict__ hA, const int* __restrict__ hB,
                      const int* __restrict__ nA, const int* __restrict__ nB,
                      const int* __restrict__ baseHA, const int* __restrict__ baseHB,
                      const int* __restrict__ baseNA, const int* __restrict__ baseNB,
                      int* __restrict__ curHA, int* __restrict__ curHB,
                      int* __restrict__ curNA, int* __restrict__ curNB,
                      int* __restrict__ nArrHA, int* __restrict__ nArrHB,
                      int* __restrict__ hArrNA, int* __restrict__ hArrNB, int E) {
  int e = blockIdx.x * 256 + threadIdx.x;
  if (e >= E) return;
  int ha = hA[e], hb = hB[e], na = nA[e], nb = nB[e];
  int p;
  p = atomicAdd(&curHA[ha], 1); nArrHA[baseHA[ha] + p] = na;
  p = atomicAdd(&curHB[hb], 1); nArrHB[baseHB[hb] + p] = nb;
  p = atomicAdd(&curNA[na], 1); hArrNA[baseNA[na] + p] = ha;
  p = atomicAdd(&curNB[nb], 1); hArrNB[baseNB[nb] + p] = hb;
}

// ---------------------------------------------------------------- Xagg gather
// Xagg[h] = sum over bucket of x_bf16[node]; written as bf16. 128 thr/row.
__global__ void xagg_gather(const unsigned short* __restrict__ X, const int* __restrict__ nArr,
                            const int* __restrict__ base, unsigned short* __restrict__ Xagg) {
  int h = blockIdx.x * 2 + (threadIdx.x >> 7);
  if (h >= NHE) return;
  int sub = threadIdx.x & 127;
  int c4 = sub << 2;
  float ax = 0.f, ay = 0.f, az = 0.f, aw = 0.f;
  int b1 = base[h + 1];
  for (int i = base[h]; i < b1; ++i) {
    int n = nArr[i];
    ushort4v v = *(const ushort4v*)&X[(size_t)n * CCH + c4];
    ax += bf2f(v[0]); ay += bf2f(v[1]); az += bf2f(v[2]); aw += bf2f(v[3]);
  }
  ushort4v r = {f2bf(ax), f2bf(ay), f2bf(az), f2bf(aw)};
  *(ushort4v*)&Xagg[(size_t)h * CCH + c4] = r;
}

// ---------------------------------------------------------------- fused attention
// One wave per node. acc = sum_e exp(scale * q.he[h_e]) * he[h_e] (UNNORMALIZED),
// written directly as bf16 (normalization folded into aW later).
// Per-head exp-sums -> per-block partials (no global atomics).
__global__ void fused_attn(const unsigned short* __restrict__ Qb,
                           const unsigned short* __restrict__ heb,
                           const int* __restrict__ hArr, const int* __restrict__ base,
                           unsigned short* __restrict__ nbf, float* __restrict__ partials) {
  __shared__ float lsum[8];
  if (threadIdx.x < 8) lsum[threadIdx.x] = 0.f;
  __syncthreads();
  int node = blockIdx.x * 4 + (threadIdx.x >> 6);   // grid covers MPAD exactly
  int lane = threadIdx.x & 63;
  int d0 = lane << 3;                               // 8 channels per lane, head = lane>>3
  float acc[8] = {0.f, 0.f, 0.f, 0.f, 0.f, 0.f, 0.f, 0.f};
  float psum = 0.f;
  if (node < NNODE) {
    ushort8 qv = *(const ushort8*)&Qb[(size_t)node * CCH + d0];
    float q[8];
#pragma unroll
    for (int j = 0; j < 8; ++j) q[j] = bf2f(qv[j]);
    int b1 = base[node + 1];
    for (int i = base[node]; i < b1; ++i) {
      int hid = hArr[i];
      ushort8 kv = *(const ushort8*)&heb[(size_t)hid * CCH + d0];
      float k[8];
#pragma unroll
      for (int j = 0; j < 8; ++j) k[j] = bf2f(kv[j]);
      float d = q[0] * k[0] + q[1] * k[1] + q[2] * k[2] + q[3] * k[3] +
                q[4] * k[4] + q[5] * k[5] + q[6] * k[6] + q[7] * k[7];
      d += __shfl_xor(d, 1); d += __shfl_xor(d, 2); d += __shfl_xor(d, 4);
      float a = __expf(d * 0.125f);   // scale = 1/sqrt(64); logits bounded, no max pass
      psum += a;
#pragma unroll
      for (int j = 0; j < 8; ++j) acc[j] += a * k[j];
    }
  }
  ushort8 r;
#pragma unroll
  for (int j = 0; j < 8; ++j) r[j] = f2bf(acc[j]);
  *(ushort8*)&nbf[(size_t)node * CCH + d0] = r;     // pad rows get zeros
  if ((lane & 7) == 0) atomicAdd(&lsum[lane >> 3], psum);
  __syncthreads();
  if (threadIdx.x < 8) partials[(size_t)blockIdx.x * 8 + threadIdx.x] = lsum[threadIdx.x];
}

// partials[nb][8] -> inv[8]; one block per head
__global__ void reduce_partials(const float* __restrict__ partials, float* __restrict__ inv, int nb) {
  __shared__ float ls[256];
  int h = blockIdx.x;
  float s = 0.f;
  for (int i = threadIdx.x; i < nb; i += 256) s += partials[(size_t)i * 8 + h];
  ls[threadIdx.x] = s;
  __syncthreads();
  for (int off = 128; off > 0; off >>= 1) {
    if (threadIdx.x < off) ls[threadIdx.x] += ls[threadIdx.x + off];
    __syncthreads();
  }
  if (threadIdx.x == 0) inv[h] = 1.0f / ls[0];
}

// ---------------------------------------------------------------- GEMM (bf16 MFMA)
// 128x128 tile, BK=32, TRUE 2-phase double-buffered LDS: stage(next) overlaps
// compute(current); ONE barrier per K-step (T3 minimum-2-phase recipe).
// 1D grid, 4 col-blocks per row-panel, XCD-swizzled so the 4 col-blocks of a
// row-panel run on the same XCD (A panel fetched once into that XCD's L2).
// out[M,512] = [A0 | A1][*,KDIM] @ Bt^T + bias-term, f32 (or bf16) out.
// ROWCNT: bias-term = (cntA[row+1]-cntA[row])*bias[col] + (cntB[row+1]-cntB[row])*bias2[col]
// else:   bias-term = bias[col] (+ bias2[col] if non-null)
// OUTBF16: write bf16 to outb instead of f32 to out.
template <int KDIM, bool ROWCNT, bool OUTBF16>
__global__ __launch_bounds__(256, 4) void gemm_bf16(
    const unsigned short* __restrict__ A0, const unsigned short* __restrict__ A1,
    const unsigned short* __restrict__ Bt, const float* __restrict__ bias,
    const float* __restrict__ bias2, const int* __restrict__ cntA,
    const int* __restrict__ cntB,
    float* __restrict__ out, unsigned short* __restrict__ outb, int M) {
  __shared__ unsigned short As[2 * 128 * 32];
  __shared__ unsigned short Bs[2 * 128 * 32];
  const int pid = xcd_pid(blockIdx.x, gridDim.x);
  const int row0 = (pid >> 2) * 128;
  const int col0 = (pid & 3) * 128;
  const int tid = threadIdx.x;
  const int lane = tid & 63;
  const int w = tid >> 6;
  const int wr = w >> 1, wc = w & 1;            // 2x2 waves -> 64x64 per wave

  auto stage = [&](int buf, int kt) {
#pragma unroll
    for (int j = 0; j < 2; ++j) {
      int c = tid + j * 256;                    // 16B chunk: row = c>>2, k8 = (c&3)*8
      int r = c >> 2, k8 = (c & 3) << 3;
      const unsigned short* asrc;
      if (KDIM == 512 || kt < 512)
        asrc = A0 + (size_t)(row0 + r) * 512 + kt + k8;
      else
        asrc = A1 + (size_t)(row0 + r) * 512 + (kt - 512) + k8;
      g2l16(asrc, &As[buf * 4096 + c * 8]);
      g2l16(Bt + (size_t)(col0 + r) * KDIM + kt + k8, &Bs[buf * 4096 + c * 8]);
    }
  };

  f32x4 acc[4][4];
#pragma unroll
  for (int m = 0; m < 4; ++m)
#pragma unroll
    for (int n = 0; n < 4; ++n) acc[m][n] = f32x4{0.f, 0.f, 0.f, 0.f};

  constexpr int NSTEP = KDIM / 32;
  stage(0, 0);
  __syncthreads();                              // buf0 ready
  int buf = 0;
  const int r16 = lane & 15, kh = (lane >> 4) << 3;
  for (int s = 0; s < NSTEP; ++s) {
    if (s + 1 < NSTEP) stage(buf ^ 1, (s + 1) * 32);   // prefetch next K-tile
    bf16x8 a[4], b[4];
#pragma unroll
    for (int m = 0; m < 4; ++m)
      a[m] = *(const bf16x8*)&As[buf * 4096 + (wr * 64 + m * 16 + r16) * 32 + kh];
#pragma unroll
    for (int n = 0; n < 4; ++n)
      b[n] = *(const bf16x8*)&Bs[buf * 4096 + (wc * 64 + n * 16 + r16) * 32 + kh];
#pragma unroll
    for (int m = 0; m < 4; ++m)
#pragma unroll
      for (int n = 0; n < 4; ++n)
        acc[m][n] = __builtin_amdgcn_mfma_f32_16x16x32_bf16(a[m], b[n], acc[m][n], 0, 0, 0);
    __syncthreads();                            // drains vmcnt: next buf ready, this buf free
    buf ^= 1;
  }
  const int cgrp = (lane >> 4) * 4;
#pragma unroll
  for (int n = 0; n < 4; ++n) {
    int col = col0 + wc * 64 + n * 16 + (lane & 15);
    float bv = bias[col];
    float bv2 = 0.f;
    if (ROWCNT) bv2 = bias2[col];
    else if (bias2) bv += bias2[col];
#pragma unroll
    for (int m = 0; m < 4; ++m) {
#pragma unroll
      for (int r2 = 0; r2 < 4; ++r2) {
        int row = row0 + wr * 64 + m * 16 + cgrp + r2;
        if (row < M) {
          size_t idx = (size_t)row * CCH + col;
          float v = acc[m][n][r2];
          if (ROWCNT)
            v += (float)(cntA[row + 1] - cntA[row]) * bv +
                 (float)(cntB[row + 1] - cntB[row]) * bv2;
          else v += bv;
          if (OUTBF16) outb[idx] = f2bf(v);
          else out[idx] = v;
        }
      }
    }
  }
}

// ---------------------------------------------------------------- LayerNorm (in-place, 1 wave / row)
__global__ void ln_kernel(float* __restrict__ y, const float* __restrict__ g,
                          const float* __restrict__ b, int nRows) {
  int row = blockIdx.x * 4 + (threadIdx.x >> 6);
  if (row >= nRows) return;
  int lane = threadIdx.x & 63;
  float* yr = y + (size_t)row * CCH;
  int d0 = lane * 8;
  float4 v0 = *(const float4*)(yr + d0);
  float4 v1 = *(const float4*)(yr + d0 + 4);
  float vv[8] = {v0.x, v0.y, v0.z, v0.w, v1.x, v1.y, v1.z, v1.w};
  float s = 0.f;
#pragma unroll
  for (int j = 0; j < 8; ++j) s += vv[j];
#pragma unroll
  for (int off = 1; off < 64; off <<= 1) s += __shfl_xor(s, off);
  float mu = s * (1.0f / 512.0f);
  float sq = 0.f;
#pragma unroll
  for (int j = 0; j < 8; ++j) { float d = vv[j] - mu; sq += d * d; }
#pragma unroll
  for (int off = 1; off < 64; off <<= 1) sq += __shfl_xor(sq, off);
  float rs = rsqrtf(sq * (1.0f / 512.0f) + 1e-5f);
  float4 g0 = *(const float4*)(g + d0), g1 = *(const float4*)(g + d0 + 4);
  float4 b0 = *(const float4*)(b + d0), b1 = *(const float4*)(b + d0 + 4);
  float gg[8] = {g0.x, g0.y, g0.z, g0.w, g1.x, g1.y, g1.z, g1.w};
  float bb[8] = {b0.x, b0.y, b0.z, b0.w, b1.x, b1.y, b1.z, b1.w};
  float o[8];
#pragma unroll
  for (int j = 0; j < 8; ++j) o[j] = gg[j] * (vv[j] - mu) * rs + bb[j];
  *(float4*)(yr + d0) = float4{o[0], o[1], o[2], o[3]};
  *(float4*)(yr + d0 + 4) = float4{o[4], o[5], o[6], o[7]};
}

// ---------------------------------------------------------------- host
extern "C" void kernel_launch(void* const* d_in, const int* in_sizes, int n_in,
                              void* d_out, int out_size, void* d_ws, size_t ws_size,
                              hipStream_t stream) {
  const float* x_a = (const float*)d_in[0];
  const float* x_b = (const float*)d_in[1];
  const int* nidx[2] = {(const int*)d_in[2], (const int*)d_in[4]};
  const int* hidx[2] = {(const int*)d_in[3], (const int*)d_in[5]};
  const float *kW[2], *kb[2], *qW[2], *qb[2], *aW[2], *ab[2], *sW[2], *sb[2], *lng[2], *lnb[2];
  for (int t = 0; t < 2; ++t) {
    int base = 7 + t * 10;
    kW[t] = (const float*)d_in[base + 0]; kb[t] = (const float*)d_in[base + 1];
    qW[t] = (const float*)d_in[base + 2]; qb[t] = (const float*)d_in[base + 3];
    aW[t] = (const float*)d_in[base + 4]; ab[t] = (const float*)d_in[base + 5];
    sW[t] = (const float*)d_in[base + 6]; sb[t] = (const float*)d_in[base + 7];
    lng[t] = (const float*)d_in[base + 8]; lnb[t] = (const float*)d_in[base + 9];
  }

  // ---------------- workspace layout
  const size_t SZ_XBF = (size_t)MPAD * CCH * 2;         // 41 MB
  const size_t SZ_HEB = (size_t)NHE * CCH * 2;          // 16.8 MB
  const size_t NBLK_ATTN = MPAD / 4;                    // 10016
  size_t off = 0;
  auto take = [&](size_t sz) { size_t o = off; off = (off + sz + 255) & ~(size_t)255; return o; };
  size_t o_xbf[2]; o_xbf[0] = take(SZ_XBF); o_xbf[1] = take(SZ_XBF);
  size_t o_wtQ[2]; o_wtQ[0] = take((size_t)512 * 512 * 2); o_wtQ[1] = take((size_t)512 * 512 * 2);
  size_t o_wtC[2]; o_wtC[0] = take((size_t)512 * 1024 * 2); o_wtC[1] = take((size_t)512 * 1024 * 2);
  size_t o_wtHE = take((size_t)512 * 1024 * 2);
  size_t o_heb = take(SZ_HEB);
  size_t o_bufP = take(SZ_XBF);                         // xagg_a+xagg_b, later qbf
  size_t o_nbf = take(SZ_XBF);
  size_t o_part = take(NBLK_ATTN * 8 * 4);
  size_t o_stats = take(256);
  size_t o_cnt4 = take((size_t)(2 * NHE + 2 * NNODE) * 4);   // 4 count/cursor arrays
  size_t o_baseH[2]; o_baseH[0] = take((NHE + 1) * 4); o_baseH[1] = take((NHE + 1) * 4);
  size_t o_baseN[2]; o_baseN[0] = take((NNODE + 1) * 4); o_baseN[1] = take((NNODE + 1) * 4);
  size_t o_nArrH[2]; o_nArrH[0] = take((size_t)NEDGE * 4); o_nArrH[1] = take((size_t)NEDGE * 4);
  size_t o_hArrN[2]; o_hArrN[0] = take((size_t)NEDGE * 4); o_hArrN[1] = take((size_t)NEDGE * 4);
  if (ws_size < off) return;

  char* ws = (char*)d_ws;
  unsigned short* xbf[2] = {(unsigned short*)(ws + o_xbf[0]), (unsigned short*)(ws + o_xbf[1])};
  unsigned short* wtQ[2] = {(unsigned short*)(ws + o_wtQ[0]), (unsigned short*)(ws + o_wtQ[1])};
  unsigned short* wtC[2] = {(unsigned short*)(ws + o_wtC[0]), (unsigned short*)(ws + o_wtC[1])};
  unsigned short* wtHE = (unsigned short*)(ws + o_wtHE);
  unsigned short* heb = (unsigned short*)(ws + o_heb);
  unsigned short* xaggA = (unsigned short*)(ws + o_bufP);
  unsigned short* xaggB = xaggA + (size_t)NHE * CCH;
  unsigned short* qbf = (unsigned short*)(ws + o_bufP);     // aliases xagg (dead after he GEMM)
  unsigned short* nbf = (unsigned short*)(ws + o_nbf);
  float* partials = (float*)(ws + o_part);
  float* inv = (float*)(ws + o_stats);
  int* cntHA = (int*)(ws + o_cnt4);
  int* cntHB = cntHA + NHE;
  int* cntNA = cntHB + NHE;
  int* cntNB = cntNA + NNODE;
  int* baseH[2] = {(int*)(ws + o_baseH[0]), (int*)(ws + o_baseH[1])};
  int* baseN[2] = {(int*)(ws + o_baseN[0]), (int*)(ws + o_baseN[1])};
  int* nArrH[2] = {(int*)(ws + o_nArrH[0]), (int*)(ws + o_nArrH[1])};
  int* hArrN[2] = {(int*)(ws + o_hArrN[0]), (int*)(ws + o_hArrN[1])};
  float* out = (float*)d_out;

  const long nValid = (long)NNODE * CCH, nTotal = (long)MPAD * CCH;
  const int cvtBlocks = (int)((nTotal / 8 + 255) / 256);
  const int gemmBlocks = 4 * (MPAD / 128);   // 1252, 1D grid (XCD-swizzled in-kernel)
  const int heBlocks = 4 * (NHE / 128);      // 512
  const int histBlocks = (NEDGE + 255) / 256;

  // ---------------- CSR builds: 1 memset + 3 kernels (was ~16 dispatches)
  hipMemsetAsync(cntHA, 0, (size_t)(2 * NHE + 2 * NNODE) * 4, stream);
  hist4<<<histBlocks, 256, 0, stream>>>(hidx[0], hidx[1], nidx[0], nidx[1],
                                        cntHA, cntHB, cntNA, cntNB, NEDGE);
  scan4<<<4, 1024, 0, stream>>>(cntHA, baseH[0], NHE, cntHB, baseH[1], NHE,
                                cntNA, baseN[0], NNODE, cntNB, baseN[1], NNODE);
  fill4<<<histBlocks, 256, 0, stream>>>(hidx[0], hidx[1], nidx[0], nidx[1],
                                        baseH[0], baseH[1], baseN[0], baseN[1],
                                        cntHA, cntHB, cntNA, cntNB,
                                        nArrH[0], nArrH[1], hArrN[0], hArrN[1], NEDGE);

  // ---------------- convert inputs / weights to bf16
  cvt_bf16_pad<<<cvtBlocks, 256, 0, stream>>>(x_a, xbf[0], nValid, nTotal);
  cvt_bf16_pad<<<cvtBlocks, 256, 0, stream>>>(x_b, xbf[1], nValid, nTotal);
  for (int t = 0; t < 2; ++t) {
    transpose_cvt<<<1024, 256, 0, stream>>>(qW[t], wtQ[t], 512, 0);
    transpose_cvt<<<1024, 256, 0, stream>>>(sW[t], wtC[t], 1024, 512);  // aW half filled later
    transpose_cvt<<<1024, 256, 0, stream>>>(kW[t], wtHE, 1024, t * 512);
  }

  // ---------------- he = [Xagg_a|Xagg_b] @ [kW_a;kW_b] + cntA*kb_a + cntB*kb_b  (bf16)
  xagg_gather<<<NHE / 2, 256, 0, stream>>>(xbf[0], nArrH[0], baseH[0], xaggA);
  xagg_gather<<<NHE / 2, 256, 0, stream>>>(xbf[1], nArrH[1], baseH[1], xaggB);
  gemm_bf16<1024, true, true><<<heBlocks, 256, 0, stream>>>(
      xaggA, xaggB, wtHE, kb[0], kb[1], baseH[0], baseH[1], nullptr, heb, NHE);

  // ---------------- per-type attention + output
  for (int t = 0; t < 2; ++t) {
    float* dout_t = out + (size_t)t * NNODE * CCH;
    // Q projection -> bf16 (qbf aliases xagg region; xagg dead after he GEMM)
    gemm_bf16<512, false, true><<<gemmBlocks, 256, 0, stream>>>(
        xbf[t], xbf[t], wtQ[t], qb[t], nullptr, nullptr, nullptr, nullptr, qbf, NNODE);
    // fused attention: unnormalized bf16 node_out + per-block head exp-sums
    fused_attn<<<(int)NBLK_ATTN, 256, 0, stream>>>(qbf, heb, hArrN[t], baseN[t], nbf, partials);
    reduce_partials<<<8, 256, 0, stream>>>(partials, inv, (int)NBLK_ATTN);
    // fold softmax denominator into aW (rows scaled by inv[head])
    transpose_cvt_scale<<<1024, 256, 0, stream>>>(aW[t], inv, wtC[t], 1024);
    // fused: out = node_out_unnorm @ (inv*aW) + ab + x @ sW + sb   (K = 1024)
    gemm_bf16<1024, false, false><<<gemmBlocks, 256, 0, stream>>>(
        nbf, xbf[t], wtC[t], ab[t], sb[t], nullptr, nullptr, dout_t, nullptr, NNODE);
    ln_kernel<<<(NNODE + 3) / 4, 256, 0, stream>>>(dout_t, lng[t], lnb[t], NNODE);
  }
}

// Round 7
// 678.967 us; speedup vs baseline: 5.9681x; 1.0606x over previous
//
#include <hip/hip_runtime.h>
#include <cstdint>

// Problem constants (match reference setup_inputs)
#define NNODE 40000
#define NEDGE 120000
#define NHE   16384
#define CCH   512
#define MPAD  40064   // 313 * 128, padded row count for GEMM A operands

typedef __attribute__((ext_vector_type(8))) short bf16x8;
typedef __attribute__((ext_vector_type(4))) float f32x4;
typedef __attribute__((ext_vector_type(8))) unsigned short ushort8;
typedef __attribute__((ext_vector_type(4))) unsigned short ushort4v;

// ---------------------------------------------------------------- helpers
__device__ __forceinline__ unsigned short f2bf(float f) {
  unsigned int u = __float_as_uint(f);
  u += 0x7FFFu + ((u >> 16) & 1u);   // round-to-nearest-even
  return (unsigned short)(u >> 16);
}
__device__ __forceinline__ float bf2f(unsigned short u) {
  return __uint_as_float((unsigned int)u << 16);
}

__device__ __forceinline__ void g2l16(const void* g, void* l) {
  // async global->LDS, 16B per lane. LDS dest must be wave-uniform base + lane*16.
  __builtin_amdgcn_global_load_lds(
      (const __attribute__((address_space(1))) unsigned int*)(uintptr_t)g,
      (__attribute__((address_space(3))) unsigned int*)(unsigned int)(uintptr_t)l,
      16, 0, 0);
}

// bijective XCD swizzle (m204): blocks with consecutive pid land on the same XCD
__device__ __forceinline__ int xcd_pid(int lin, int nwg) {
  int xcd = lin & 7, slot = lin >> 3;
  int q = nwg >> 3, r = nwg & 7;
  return ((xcd < r) ? (xcd * (q + 1)) : (r * (q + 1) + (xcd - r) * q)) + slot;
}

// ---------------------------------------------------------------- conversions (merged)
// both x_a and x_b in one dispatch; grid = 2*half
__global__ void cvt2(const float* __restrict__ xa, const float* __restrict__ xb,
                     unsigned short* __restrict__ oa, unsigned short* __restrict__ ob,
                     long nValid, long nTotal, int half) {
  int t = blockIdx.x >= half;
  long i = ((long)(blockIdx.x - t * half) * 256 + threadIdx.x) * 8;
  if (i >= nTotal) return;
  const float* in = t ? xb : xa;
  unsigned short* out = t ? ob : oa;
  ushort8 r;
  if (i < nValid) {
    float4 a = *(const float4*)(in + i);
    float4 b = *(const float4*)(in + i + 4);
    r[0] = f2bf(a.x); r[1] = f2bf(a.y); r[2] = f2bf(a.z); r[3] = f2bf(a.w);
    r[4] = f2bf(b.x); r[5] = f2bf(b.y); r[6] = f2bf(b.z); r[7] = f2bf(b.w);
  } else {
    for (int j = 0; j < 8; ++j) r[j] = 0;
  }
  *(ushort8*)(out + i) = r;
}

// 6 weight transposes (f32 [512][512] -> bf16 [col][ld]+kOff) in ONE dispatch
struct TPack {
  const float* W[6];
  unsigned short* Wt[6];
  int ld[6];
  int kOff[6];
};
__global__ void transpose_cvt6(TPack p) {
  int which = blockIdx.x >> 10;                 // 1024 blocks per matrix
  int gid = (blockIdx.x & 1023) * 256 + threadIdx.x;
  int i = gid >> 9, j = gid & 511;              // W[i][j]
  p.Wt[which][(size_t)j * p.ld[which] + p.kOff[which] + i] = f2bf(p.W[which][gid]);
}

// aW for both types, rows scaled by inv[t*8 + head(k)] (folds softmax denominator)
__global__ void tscale2(const float* __restrict__ Wa, const float* __restrict__ Wb,
                        const float* __restrict__ inv,
                        unsigned short* __restrict__ Wta, unsigned short* __restrict__ Wtb) {
  int t = blockIdx.x >> 10;
  int gid = (blockIdx.x & 1023) * 256 + threadIdx.x;
  int i = gid >> 9, j = gid & 511;              // W[i][j], i is the k index
  const float* W = t ? Wb : Wa;
  unsigned short* Wt = t ? Wtb : Wta;
  Wt[(size_t)j * 1024 + i] = f2bf(W[gid] * inv[t * 8 + (i >> 6)]);
}

// ---------------------------------------------------------------- CSR build (collapsed)
__global__ void hist4(const int* __restrict__ hA, const int* __restrict__ hB,
                      const int* __restrict__ nA, const int* __restrict__ nB,
                      int* __restrict__ cntHA, int* __restrict__ cntHB,
                      int* __restrict__ cntNA, int* __restrict__ cntNB, int E) {
  int e = blockIdx.x * 256 + threadIdx.x;
  if (e >= E) return;
  atomicAdd(&cntHA[hA[e]], 1);
  atomicAdd(&cntHB[hB[e]], 1);
  atomicAdd(&cntNA[nA[e]], 1);
  atomicAdd(&cntNB[nB[e]], 1);
}

// 4 independent single-block exclusive scans; zeroes cnt in place (becomes cursor)
__global__ void scan4(int* __restrict__ c0, int* __restrict__ b0, int n0,
                      int* __restrict__ c1, int* __restrict__ b1, int n1,
                      int* __restrict__ c2, int* __restrict__ b2, int n2,
                      int* __restrict__ c3, int* __restrict__ b3, int n3) {
  __shared__ int part[1024];
  int* cnt; int* base; int n;
  if (blockIdx.x == 0) { cnt = c0; base = b0; n = n0; }
  else if (blockIdx.x == 1) { cnt = c1; base = b1; n = n1; }
  else if (blockIdx.x == 2) { cnt = c2; base = b2; n = n2; }
  else { cnt = c3; base = b3; n = n3; }
  int tid = threadIdx.x;
  int chunk = (n + 1023) >> 10;
  int lo = tid * chunk;
  int hi = lo + chunk; if (hi > n) hi = n;
  int s = 0;
  for (int i = lo; i < hi; ++i) s += cnt[i];
  part[tid] = s;
  __syncthreads();
  for (int off = 1; off < 1024; off <<= 1) {
    int v = (tid >= off) ? part[tid - off] : 0;
    __syncthreads();
    part[tid] += v;
    __syncthreads();
  }
  int excl = (tid == 0) ? 0 : part[tid - 1];
  for (int i = lo; i < hi; ++i) { base[i] = excl; excl += cnt[i]; cnt[i] = 0; }
  if (tid == 0) base[n] = part[1023];
}

// fills all 4 CSR value arrays (he-CSR stores node ids; node-CSR stores he ids)
__global__ void fill4(const int* __restrict__ hA, const int* __restrict__ hB,
                      const int* __restrict__ nA, const int* __restrict__ nB,
                      const int* __restrict__ baseHA, const int* __restrict__ baseHB,
                      const int* __restrict__ baseNA, const int* __restrict__ baseNB,
                      int* __restrict__ curHA, int* __restrict__ curHB,
                      int* __restrict__ curNA, int* __restrict__ curNB,
                      int* __restrict__ nArrHA, int* __restrict__ nArrHB,
                      int* __restrict__ hArrNA, int* __restrict__ hArrNB, int E) {
  int e = blockIdx.x * 256 + threadIdx.x;
  if (e >= E) return;
  int ha = hA[e], hb = hB[e], na = nA[e], nb = nB[e];
  int p;
  p = atomicAdd(&curHA[ha], 1); nArrHA[baseHA[ha] + p] = na;
  p = atomicAdd(&curHB[hb], 1); nArrHB[baseHB[hb] + p] = nb;
  p = atomicAdd(&curNA[na], 1); hArrNA[baseNA[na] + p] = ha;
  p = atomicAdd(&curNB[nb], 1); hArrNB[baseNB[nb] + p] = hb;
}

// ---------------------------------------------------------------- Xagg gather (both types)
__global__ void xagg2(const unsigned short* __restrict__ Xa, const int* __restrict__ nArrA,
                      const int* __restrict__ baseA, unsigned short* __restrict__ Oa,
                      const unsigned short* __restrict__ Xb, const int* __restrict__ nArrB,
                      const int* __restrict__ baseB, unsigned short* __restrict__ Ob, int half) {
  int t = blockIdx.x >= half;
  int bl = blockIdx.x - t * half;
  const unsigned short* X = t ? Xb : Xa;
  const int* nArr = t ? nArrB : nArrA;
  const int* base = t ? baseB : baseA;
  unsigned short* Xagg = t ? Ob : Oa;
  int h = bl * 2 + (threadIdx.x >> 7);
  if (h >= NHE) return;
  int sub = threadIdx.x & 127;
  int c4 = sub << 2;
  float ax = 0.f, ay = 0.f, az = 0.f, aw = 0.f;
  int b1 = base[h + 1];
  for (int i = base[h]; i < b1; ++i) {
    int n = nArr[i];
    ushort4v v = *(const ushort4v*)&X[(size_t)n * CCH + c4];
    ax += bf2f(v[0]); ay += bf2f(v[1]); az += bf2f(v[2]); aw += bf2f(v[3]);
  }
  ushort4v r = {f2bf(ax), f2bf(ay), f2bf(az), f2bf(aw)};
  *(ushort4v*)&Xagg[(size_t)h * CCH + c4] = r;
}

// ---------------------------------------------------------------- fused attention (both types)
// One wave per node. acc = sum_e exp(scale * q.he[h_e]) * he[h_e] (UNNORMALIZED),
// written as bf16 (normalization folded into aW later). hArr prefetched 1 ahead.
__global__ void fused_attn2(const unsigned short* __restrict__ Qa,
                            const unsigned short* __restrict__ Qbb,
                            const unsigned short* __restrict__ heb,
                            const int* __restrict__ hArrA, const int* __restrict__ baseA,
                            const int* __restrict__ hArrB, const int* __restrict__ baseB,
                            unsigned short* __restrict__ nbfA, unsigned short* __restrict__ nbfB,
                            float* __restrict__ partials, int half) {
  __shared__ float lsum[8];
  if (threadIdx.x < 8) lsum[threadIdx.x] = 0.f;
  __syncthreads();
  int t = blockIdx.x >= half;
  int bl = blockIdx.x - t * half;
  const unsigned short* Qb = t ? Qbb : Qa;
  const int* hArr = t ? hArrB : hArrA;
  const int* base = t ? baseB : baseA;
  unsigned short* nbf = t ? nbfB : nbfA;
  int node = bl * 4 + (threadIdx.x >> 6);           // covers MPAD exactly
  int lane = threadIdx.x & 63;
  int d0 = lane << 3;                               // 8 channels per lane, head = lane>>3
  float acc[8] = {0.f, 0.f, 0.f, 0.f, 0.f, 0.f, 0.f, 0.f};
  float psum = 0.f;
  if (node < NNODE) {
    ushort8 qv = *(const ushort8*)&Qb[(size_t)node * CCH + d0];
    float q[8];
#pragma unroll
    for (int j = 0; j < 8; ++j) q[j] = bf2f(qv[j]);
    int i0 = base[node], i1 = base[node + 1];
    int hid_n = (i0 < i1) ? hArr[i0] : 0;
    for (int i = i0; i < i1; ++i) {
      int hid = hid_n;
      hid_n = (i + 1 < i1) ? hArr[i + 1] : 0;       // prefetch next edge id
      ushort8 kv = *(const ushort8*)&heb[(size_t)hid * CCH + d0];
      float k[8];
#pragma unroll
      for (int j = 0; j < 8; ++j) k[j] = bf2f(kv[j]);
      float d = q[0] * k[0] + q[1] * k[1] + q[2] * k[2] + q[3] * k[3] +
                q[4] * k[4] + q[5] * k[5] + q[6] * k[6] + q[7] * k[7];
      d += __shfl_xor(d, 1); d += __shfl_xor(d, 2); d += __shfl_xor(d, 4);
      float a = __expf(d * 0.125f);   // scale = 1/sqrt(64); logits bounded, no max pass
      psum += a;
#pragma unroll
      for (int j = 0; j < 8; ++j) acc[j] += a * k[j];
    }
  }
  ushort8 r;
#pragma unroll
  for (int j = 0; j < 8; ++j) r[j] = f2bf(acc[j]);
  *(ushort8*)&nbf[(size_t)node * CCH + d0] = r;     // pad rows get zeros
  if ((lane & 7) == 0) atomicAdd(&lsum[lane >> 3], psum);
  __syncthreads();
  if (threadIdx.x < 8) partials[(size_t)blockIdx.x * 8 + threadIdx.x] = lsum[threadIdx.x];
}

// partials[2*half][8] -> inv[16]; one block per (type,head)
__global__ void reduce_partials2(const float* __restrict__ partials, float* __restrict__ inv,
                                 int half) {
  __shared__ float ls[256];
  int hh = blockIdx.x;                    // 0..15
  int t = hh >> 3, h = hh & 7;
  float s = 0.f;
  for (int i = threadIdx.x; i < half; i += 256) s += partials[(size_t)(t * half + i) * 8 + h];
  ls[threadIdx.x] = s;
  __syncthreads();
  for (int off = 128; off > 0; off >>= 1) {
    if (threadIdx.x < off) ls[threadIdx.x] += ls[threadIdx.x + off];
    __syncthreads();
  }
  if (threadIdx.x == 0) inv[hh] = 1.0f / ls[0];
}

// ---------------------------------------------------------------- GEMM body (bf16 MFMA)
// 128x128 tile, BK=32, 2-phase double-buffered LDS (stage(next) || compute(cur)),
// one barrier per K-step. pid selects (row0, col0): 4 col-blocks per row-panel.
template <int KDIM, bool ROWCNT, bool OUTBF16>
__device__ __forceinline__ void gemm_body(
    unsigned short* As, unsigned short* Bs, int pid,
    const unsigned short* __restrict__ A0, const unsigned short* __restrict__ A1,
    const unsigned short* __restrict__ Bt, const float* __restrict__ bias,
    const float* __restrict__ bias2, const int* __restrict__ cntA,
    const int* __restrict__ cntB,
    float* __restrict__ out, unsigned short* __restrict__ outb, int M) {
  const int row0 = (pid >> 2) * 128;
  const int col0 = (pid & 3) * 128;
  const int tid = threadIdx.x;
  const int lane = tid & 63;
  const int w = tid >> 6;
  const int wr = w >> 1, wc = w & 1;            // 2x2 waves -> 64x64 per wave

  auto stage = [&](int buf, int kt) {
#pragma unroll
    for (int j = 0; j < 2; ++j) {
      int c = tid + j * 256;                    // 16B chunk: row = c>>2, k8 = (c&3)*8
      int r = c >> 2, k8 = (c & 3) << 3;
      const unsigned short* asrc;
      if (KDIM == 512 || kt < 512)
        asrc = A0 + (size_t)(row0 + r) * 512 + kt + k8;
      else
        asrc = A1 + (size_t)(row0 + r) * 512 + (kt - 512) + k8;
      g2l16(asrc, &As[buf * 4096 + c * 8]);
      g2l16(Bt + (size_t)(col0 + r) * KDIM + kt + k8, &Bs[buf * 4096 + c * 8]);
    }
  };

  f32x4 acc[4][4];
#pragma unroll
  for (int m = 0; m < 4; ++m)
#pragma unroll
    for (int n = 0; n < 4; ++n) acc[m][n] = f32x4{0.f, 0.f, 0.f, 0.f};

  constexpr int NSTEP = KDIM / 32;
  stage(0, 0);
  __syncthreads();                              // buf0 ready
  int buf = 0;
  const int r16 = lane & 15, kh = (lane >> 4) << 3;
  for (int s = 0; s < NSTEP; ++s) {
    if (s + 1 < NSTEP) stage(buf ^ 1, (s + 1) * 32);   // prefetch next K-tile
    bf16x8 a[4], b[4];
#pragma unroll
    for (int m = 0; m < 4; ++m)
      a[m] = *(const bf16x8*)&As[buf * 4096 + (wr * 64 + m * 16 + r16) * 32 + kh];
#pragma unroll
    for (int n = 0; n < 4; ++n)
      b[n] = *(const bf16x8*)&Bs[buf * 4096 + (wc * 64 + n * 16 + r16) * 32 + kh];
#pragma unroll
    for (int m = 0; m < 4; ++m)
#pragma unroll
      for (int n = 0; n < 4; ++n)
        acc[m][n] = __builtin_amdgcn_mfma_f32_16x16x32_bf16(a[m], b[n], acc[m][n], 0, 0, 0);
    __syncthreads();                            // drains vmcnt: next buf ready, this buf free
    buf ^= 1;
  }
  const int cgrp = (lane >> 4) * 4;
#pragma unroll
  for (int n = 0; n < 4; ++n) {
    int col = col0 + wc * 64 + n * 16 + (lane & 15);
    float bv = bias[col];
    float bv2 = 0.f;
    if (ROWCNT) bv2 = bias2[col];
    else if (bias2) bv += bias2[col];
#pragma unroll
    for (int m = 0; m < 4; ++m) {
#pragma unroll
      for (int r2 = 0; r2 < 4; ++r2) {
        int row = row0 + wr * 64 + m * 16 + cgrp + r2;
        if (row < M) {
          size_t idx = (size_t)row * CCH + col;
          float v = acc[m][n][r2];
          if (ROWCNT)
            v += (float)(cntA[row + 1] - cntA[row]) * bv +
                 (float)(cntB[row + 1] - cntB[row]) * bv2;
          else v += bv;
          if (OUTBF16) outb[idx] = f2bf(v);
          else out[idx] = v;
        }
      }
    }
  }
}

// he GEMM: he = [XaggA|XaggB] @ [kWa;kWb] + cntA*kbA + cntB*kbB  (bf16 out)
__global__ __launch_bounds__(256, 4) void gemm_he(
    const unsigned short* __restrict__ A0, const unsigned short* __restrict__ A1,
    const unsigned short* __restrict__ Bt, const float* __restrict__ kbA,
    const float* __restrict__ kbB, const int* __restrict__ cntA,
    const int* __restrict__ cntB, unsigned short* __restrict__ outb, int M) {
  __shared__ unsigned short As[2 * 128 * 32];
  __shared__ unsigned short Bs[2 * 128 * 32];
  int pid = xcd_pid(blockIdx.x, gridDim.x);
  gemm_body<1024, true, true>(As, Bs, pid, A0, A1, Bt, kbA, kbB, cntA, cntB,
                              nullptr, outb, M);
}

// dual Q GEMM (both types in one launch, bf16 out)
__global__ __launch_bounds__(256, 4) void gemm_q2(
    int G1,
    const unsigned short* __restrict__ Aa, const unsigned short* __restrict__ Bta,
    const float* __restrict__ biasa, unsigned short* __restrict__ outa,
    const unsigned short* __restrict__ Ab, const unsigned short* __restrict__ Btb,
    const float* __restrict__ biasb, unsigned short* __restrict__ outbB) {
  __shared__ unsigned short As[2 * 128 * 32];
  __shared__ unsigned short Bs[2 * 128 * 32];
  int pid = xcd_pid(blockIdx.x, gridDim.x);
  if (pid < G1)
    gemm_body<512, false, true>(As, Bs, pid, Aa, Aa, Bta, biasa, nullptr,
                                nullptr, nullptr, nullptr, outa, NNODE);
  else
    gemm_body<512, false, true>(As, Bs, pid - G1, Ab, Ab, Btb, biasb, nullptr,
                                nullptr, nullptr, nullptr, outbB, NNODE);
}

// dual combined GEMM: out = nbf @ (inv*aW) + ab + x @ sW + sb   (K=1024, f32 out)
__global__ __launch_bounds__(256, 4) void gemm_c2(
    int G1,
    const unsigned short* __restrict__ A0a, const unsigned short* __restrict__ A1a,
    const unsigned short* __restrict__ Bta, const float* __restrict__ aba,
    const float* __restrict__ sba, float* __restrict__ outa,
    const unsigned short* __restrict__ A0b, const unsigned short* __restrict__ A1b,
    const unsigned short* __restrict__ Btb, const float* __restrict__ abb,
    const float* __restrict__ sbb, float* __restrict__ outb) {
  __shared__ unsigned short As[2 * 128 * 32];
  __shared__ unsigned short Bs[2 * 128 * 32];
  int pid = xcd_pid(blockIdx.x, gridDim.x);
  if (pid < G1)
    gemm_body<1024, false, false>(As, Bs, pid, A0a, A1a, Bta, aba, sba,
                                  nullptr, nullptr, outa, nullptr, NNODE);
  else
    gemm_body<1024, false, false>(As, Bs, pid - G1, A0b, A1b, Btb, abb, sbb,
                                  nullptr, nullptr, outb, nullptr, NNODE);
}

// ---------------------------------------------------------------- LayerNorm (both types, in-place)
__global__ void ln2(float* __restrict__ y, const float* __restrict__ ga,
                    const float* __restrict__ ba, const float* __restrict__ gb,
                    const float* __restrict__ bb) {
  int row = blockIdx.x * 4 + (threadIdx.x >> 6);
  if (row >= 2 * NNODE) return;
  int t = row >= NNODE;
  const float* g = t ? gb : ga;
  const float* b = t ? bb : ba;
  int lane = threadIdx.x & 63;
  float* yr = y + (size_t)row * CCH;
  int d0 = lane * 8;
  float4 v0 = *(const float4*)(yr + d0);
  float4 v1 = *(const float4*)(yr + d0 + 4);
  float vv[8] = {v0.x, v0.y, v0.z, v0.w, v1.x, v1.y, v1.z, v1.w};
  float s = 0.f;
#pragma unroll
  for (int j = 0; j < 8; ++j) s += vv[j];
#pragma unroll
  for (int off = 1; off < 64; off <<= 1) s += __shfl_xor(s, off);
  float mu = s * (1.0f / 512.0f);
  float sq = 0.f;
#pragma unroll
  for (int j = 0; j < 8; ++j) { float d = vv[j] - mu; sq += d * d; }
#pragma unroll
  for (int off = 1; off < 64; off <<= 1) sq += __shfl_xor(sq, off);
  float rs = rsqrtf(sq * (1.0f / 512.0f) + 1e-5f);
  float4 g0 = *(const float4*)(g + d0), g1 = *(const float4*)(g + d0 + 4);
  float4 b0 = *(const float4*)(b + d0), b1 = *(const float4*)(b + d0 + 4);
  float gg[8] = {g0.x, g0.y, g0.z, g0.w, g1.x, g1.y, g1.z, g1.w};
  float bbv[8] = {b0.x, b0.y, b0.z, b0.w, b1.x, b1.y, b1.z, b1.w};
  float o[8];
#pragma unroll
  for (int j = 0; j < 8; ++j) o[j] = gg[j] * (vv[j] - mu) * rs + bbv[j];
  *(float4*)(yr + d0) = float4{o[0], o[1], o[2], o[3]};
  *(float4*)(yr + d0 + 4) = float4{o[4], o[5], o[6], o[7]};
}

// ---------------------------------------------------------------- host
extern "C" void kernel_launch(void* const* d_in, const int* in_sizes, int n_in,
                              void* d_out, int out_size, void* d_ws, size_t ws_size,
                              hipStream_t stream) {
  const float* x_a = (const float*)d_in[0];
  const float* x_b = (const float*)d_in[1];
  const int* nidx[2] = {(const int*)d_in[2], (const int*)d_in[4]};
  const int* hidx[2] = {(const int*)d_in[3], (const int*)d_in[5]};
  const float *kW[2], *kb[2], *qW[2], *qb[2], *aW[2], *ab[2], *sW[2], *sb[2], *lng[2], *lnb[2];
  for (int t = 0; t < 2; ++t) {
    int base = 7 + t * 10;
    kW[t] = (const float*)d_in[base + 0]; kb[t] = (const float*)d_in[base + 1];
    qW[t] = (const float*)d_in[base + 2]; qb[t] = (const float*)d_in[base + 3];
    aW[t] = (const float*)d_in[base + 4]; ab[t] = (const float*)d_in[base + 5];
    sW[t] = (const float*)d_in[base + 6]; sb[t] = (const float*)d_in[base + 7];
    lng[t] = (const float*)d_in[base + 8]; lnb[t] = (const float*)d_in[base + 9];
  }

  // ---------------- workspace layout
  const size_t SZ_XBF = (size_t)MPAD * CCH * 2;         // 41 MB
  const size_t SZ_HEB = (size_t)NHE * CCH * 2;          // 16.8 MB
  const int NBLK_ATTN = MPAD / 4;                       // 10016 per type
  size_t off = 0;
  auto take = [&](size_t sz) { size_t o = off; off = (off + sz + 255) & ~(size_t)255; return o; };
  size_t o_xbf[2]; o_xbf[0] = take(SZ_XBF); o_xbf[1] = take(SZ_XBF);
  size_t o_wtQ[2]; o_wtQ[0] = take((size_t)512 * 512 * 2); o_wtQ[1] = take((size_t)512 * 512 * 2);
  size_t o_wtC[2]; o_wtC[0] = take((size_t)512 * 1024 * 2); o_wtC[1] = take((size_t)512 * 1024 * 2);
  size_t o_wtHE = take((size_t)512 * 1024 * 2);
  size_t o_heb = take(SZ_HEB);
  size_t o_qbf = take(2 * SZ_XBF);                      // qbf_a, qbf_b
  size_t o_nbf = take(2 * SZ_XBF);                      // first xaggA/B, later nbf_a, nbf_b
  size_t o_part = take((size_t)2 * NBLK_ATTN * 8 * 4);
  size_t o_stats = take(256);
  size_t o_cnt4 = take((size_t)(2 * NHE + 2 * NNODE) * 4);
  size_t o_baseH[2]; o_baseH[0] = take((NHE + 1) * 4); o_baseH[1] = take((NHE + 1) * 4);
  size_t o_baseN[2]; o_baseN[0] = take((NNODE + 1) * 4); o_baseN[1] = take((NNODE + 1) * 4);
  size_t o_nArrH[2]; o_nArrH[0] = take((size_t)NEDGE * 4); o_nArrH[1] = take((size_t)NEDGE * 4);
  size_t o_hArrN[2]; o_hArrN[0] = take((size_t)NEDGE * 4); o_hArrN[1] = take((size_t)NEDGE * 4);
  if (ws_size < off) return;

  char* ws = (char*)d_ws;
  unsigned short* xbf[2] = {(unsigned short*)(ws + o_xbf[0]), (unsigned short*)(ws + o_xbf[1])};
  unsigned short* wtQ[2] = {(unsigned short*)(ws + o_wtQ[0]), (unsigned short*)(ws + o_wtQ[1])};
  unsigned short* wtC[2] = {(unsigned short*)(ws + o_wtC[0]), (unsigned short*)(ws + o_wtC[1])};
  unsigned short* wtHE = (unsigned short*)(ws + o_wtHE);
  unsigned short* heb = (unsigned short*)(ws + o_heb);
  unsigned short* qbf[2] = {(unsigned short*)(ws + o_qbf),
                            (unsigned short*)(ws + o_qbf) + (size_t)MPAD * CCH};
  unsigned short* xaggA = (unsigned short*)(ws + o_nbf);      // aliases nbf region (dead after he GEMM)
  unsigned short* xaggB = xaggA + (size_t)NHE * CCH;
  unsigned short* nbf[2] = {(unsigned short*)(ws + o_nbf),
                            (unsigned short*)(ws + o_nbf) + (size_t)MPAD * CCH};
  float* partials = (float*)(ws + o_part);
  float* inv = (float*)(ws + o_stats);                        // 16 entries
  int* cntHA = (int*)(ws + o_cnt4);
  int* cntHB = cntHA + NHE;
  int* cntNA = cntHB + NHE;
  int* cntNB = cntNA + NNODE;
  int* baseH[2] = {(int*)(ws + o_baseH[0]), (int*)(ws + o_baseH[1])};
  int* baseN[2] = {(int*)(ws + o_baseN[0]), (int*)(ws + o_baseN[1])};
  int* nArrH[2] = {(int*)(ws + o_nArrH[0]), (int*)(ws + o_nArrH[1])};
  int* hArrN[2] = {(int*)(ws + o_hArrN[0]), (int*)(ws + o_hArrN[1])};
  float* out = (float*)d_out;

  const long nValid = (long)NNODE * CCH, nTotal = (long)MPAD * CCH;
  const int cvtHalf = (int)((nTotal / 8 + 255) / 256);   // 10016
  const int gemmBlocks = 4 * (MPAD / 128);               // 1252 per type
  const int heBlocks = 4 * (NHE / 128);                  // 512
  const int histBlocks = (NEDGE + 255) / 256;

  // 1-4: CSR build (1 memset + 3 kernels)
  hipMemsetAsync(cntHA, 0, (size_t)(2 * NHE + 2 * NNODE) * 4, stream);
  hist4<<<histBlocks, 256, 0, stream>>>(hidx[0], hidx[1], nidx[0], nidx[1],
                                        cntHA, cntHB, cntNA, cntNB, NEDGE);
  scan4<<<4, 1024, 0, stream>>>(cntHA, baseH[0], NHE, cntHB, baseH[1], NHE,
                                cntNA, baseN[0], NNODE, cntNB, baseN[1], NNODE);
  fill4<<<histBlocks, 256, 0, stream>>>(hidx[0], hidx[1], nidx[0], nidx[1],
                                        baseH[0], baseH[1], baseN[0], baseN[1],
                                        cntHA, cntHB, cntNA, cntNB,
                                        nArrH[0], nArrH[1], hArrN[0], hArrN[1], NEDGE);

  // 5: both x -> bf16
  cvt2<<<2 * cvtHalf, 256, 0, stream>>>(x_a, x_b, xbf[0], xbf[1], nValid, nTotal, cvtHalf);

  // 6: all 6 weight transposes in one dispatch
  TPack tp;
  tp.W[0] = qW[0]; tp.Wt[0] = wtQ[0]; tp.ld[0] = 512;  tp.kOff[0] = 0;
  tp.W[1] = qW[1]; tp.Wt[1] = wtQ[1]; tp.ld[1] = 512;  tp.kOff[1] = 0;
  tp.W[2] = sW[0]; tp.Wt[2] = wtC[0]; tp.ld[2] = 1024; tp.kOff[2] = 512;
  tp.W[3] = sW[1]; tp.Wt[3] = wtC[1]; tp.ld[3] = 1024; tp.kOff[3] = 512;
  tp.W[4] = kW[0]; tp.Wt[4] = wtHE;   tp.ld[4] = 1024; tp.kOff[4] = 0;
  tp.W[5] = kW[1]; tp.Wt[5] = wtHE;   tp.ld[5] = 1024; tp.kOff[5] = 512;
  transpose_cvt6<<<6 * 1024, 256, 0, stream>>>(tp);

  // 7: both Xagg gathers
  xagg2<<<2 * (NHE / 2), 256, 0, stream>>>(xbf[0], nArrH[0], baseH[0], xaggA,
                                           xbf[1], nArrH[1], baseH[1], xaggB, NHE / 2);

  // 8: he = [XaggA|XaggB] @ [kWa;kWb] + cnt*kb (bf16)
  gemm_he<<<heBlocks, 256, 0, stream>>>(xaggA, xaggB, wtHE, kb[0], kb[1],
                                        baseH[0], baseH[1], heb, NHE);

  // 9: both Q projections -> bf16
  gemm_q2<<<2 * gemmBlocks, 256, 0, stream>>>(gemmBlocks,
                                              xbf[0], wtQ[0], qb[0], qbf[0],
                                              xbf[1], wtQ[1], qb[1], qbf[1]);

  // 10: both fused attentions (overwrites xagg region with nbf)
  fused_attn2<<<2 * NBLK_ATTN, 256, 0, stream>>>(qbf[0], qbf[1], heb,
                                                 hArrN[0], baseN[0], hArrN[1], baseN[1],
                                                 nbf[0], nbf[1], partials, NBLK_ATTN);

  // 11: softmax denominators for both types
  reduce_partials2<<<16, 256, 0, stream>>>(partials, inv, NBLK_ATTN);

  // 12: fold denominators into aW halves of wtC (both types)
  tscale2<<<2 * 1024, 256, 0, stream>>>(aW[0], aW[1], inv, wtC[0], wtC[1]);

  // 13: both combined GEMMs: out = nbf @ (inv*aW) + ab + x @ sW + sb
  gemm_c2<<<2 * gemmBlocks, 256, 0, stream>>>(gemmBlocks,
                                              nbf[0], xbf[0], wtC[0], ab[0], sb[0], out,
                                              nbf[1], xbf[1], wtC[1], ab[1], sb[1],
                                              out + (size_t)NNODE * CCH);

  // 14: LayerNorm both types, in-place
  ln2<<<(2 * NNODE + 3) / 4, 256, 0, stream>>>(out, lng[0], lnb[0], lng[1], lnb[1]);
}